// Round 15
// baseline (573.058 us; speedup 1.0000x reference)
//
#include <hip/hip_runtime.h>
#include <math.h>

#define T 32000
#define B 8
#define RES 32
#define SKIPC 32
#define NDIL 10
#define NLAYERS 20

typedef __attribute__((ext_vector_type(8))) _Float16 half8;
typedef __attribute__((ext_vector_type(4))) _Float16 half4;
typedef __attribute__((ext_vector_type(4))) float float4v;

// ---------------- fast transcendentals ----------------
__device__ __forceinline__ float fast_rcp(float x) { return __builtin_amdgcn_rcpf(x); }
__device__ __forceinline__ float fast_exp2(float x) { return __builtin_amdgcn_exp2f(x); }
__device__ __forceinline__ float fast_sigmoid(float x) {
    return fast_rcp(1.f + fast_exp2(-1.4426950408889634f * x));
}
__device__ __forceinline__ float fast_tanh(float x) {
    return 1.f - 2.f * fast_rcp(1.f + fast_exp2(2.8853900817779268f * x));
}

// ---------------- weight repack to fp16 ----------------
// res_w1: [10][64][32][3] -> w1f: [10][3][64][32] fp16  (tap-major, c contig)
// res_w2: [10][64][32]    -> w2f: [10][64][32] fp16
__global__ void repack_weights_f16(const float* __restrict__ w1,
                                   const float* __restrict__ w2,
                                   _Float16* __restrict__ w1f,
                                   _Float16* __restrict__ w2f) {
    int idx = blockIdx.x * blockDim.x + threadIdx.x;
    if (idx < NDIL * 3 * 64 * 32) {
        int i = idx;
        int c = i % 32; i /= 32;
        int o = i % 64; i /= 64;
        int kt = i % 3; i /= 3;
        int l = i;
        w1f[idx] = (_Float16)w1[((l * 64 + o) * 32 + c) * 3 + kt];
    }
    if (idx < NDIL * 64 * 32) {
        w2f[idx] = (_Float16)w2[idx];
    }
}

// ---------------- conv1: [B,1,T] -> h[B][T][RES] fp16 channel-contiguous ----
__global__ void conv1_kernel(const float* __restrict__ x,
                             const float* __restrict__ w,   // [32][1][3]
                             _Float16* __restrict__ h) {
    int t = blockIdx.x * blockDim.x + threadIdx.x;
    int b = blockIdx.y;
    if (t >= T) return;
    const float* xb = x + (size_t)b * T;
    float x2 = xb[t];
    float x1 = (t >= 1) ? xb[t - 1] : 0.f;
    float x0 = (t >= 2) ? xb[t - 2] : 0.f;
    _Float16* hr = h + ((size_t)b * T + t) * RES;
#pragma unroll
    for (int o = 0; o < RES; o += 8) {
        half8 v;
#pragma unroll
        for (int r = 0; r < 8; r++)
            v[r] = (_Float16)(w[(o + r) * 3 + 0] * x0 + w[(o + r) * 3 + 1] * x1
                            + w[(o + r) * 3 + 2] * x2);
        *(half8*)(hr + o) = v;
    }
}

// ---------------- residual layer via f16 MFMA, fp16 h + fp16 skip -----------
// h fp16 [B][T][32]: B-fragment = ONE 16-byte half8 load. skip fp16.
// G exchange intra-wave via wave-private LDS slab + wave_barrier.
// R15: __launch_bounds__(256, 8) pins VGPR <= 64 so all 2000 blocks are
// co-resident (8 blk/CU) in ONE dispatch round — R14's ~80 VGPR allowed only
// 6 blk/CU -> 2 rounds -> ~2x the BW-floor time. Spill tripwire: WRITE_SIZE.
template <bool FIRST>
__global__ __launch_bounds__(256, 8) void res_layer_mfma(
        const _Float16* __restrict__ h_in, _Float16* __restrict__ h_out,
        _Float16* __restrict__ skip,
        const _Float16* __restrict__ w1l,   // [3][64][32] this layer
        const _Float16* __restrict__ w2l,   // [64][32] this layer
        int d) {
    __shared__ _Float16 Gs[4][32][40];      // 10240 B, per-wave slabs

    const int tid = threadIdx.x;
    const int t0 = blockIdx.x * 128;
    const int b = blockIdx.y;
    const int lane = tid & 63;
    const int wv = tid >> 6;
    const int n0 = wv * 32;
    const int lcol = lane & 15;
    const int q = lane >> 4;
    const _Float16* hb = h_in + (size_t)b * T * RES;

    // ---- direct B-frag loads: 6 x one half8 ----
    half8 bf[2][3];
    const half8 zero8 = (half8)(_Float16)0.f;
    if (t0 >= 2 * d) {                      // interior block (uniform branch)
#pragma unroll
        for (int nt = 0; nt < 2; nt++)
#pragma unroll
            for (int kt = 0; kt < 3; kt++) {
                int tb = t0 + n0 + nt * 16 + lcol - (2 - kt) * d;
                bf[nt][kt] = *(const half8*)(hb + (size_t)tb * RES + q * 8);
            }
    } else {
#pragma unroll
        for (int nt = 0; nt < 2; nt++)
#pragma unroll
            for (int kt = 0; kt < 3; kt++) {
                int tb = t0 + n0 + nt * 16 + lcol - (2 - kt) * d;
                bool ok = tb >= 0;
                half8 p = *(const half8*)(hb + (size_t)(ok ? tb : 0) * RES + q * 8);
                bf[nt][kt] = ok ? p : zero8;
            }
    }

    // ---- GEMM1: conv ----
    float4v acc[4][2];
#pragma unroll
    for (int mt = 0; mt < 4; mt++)
#pragma unroll
        for (int nt = 0; nt < 2; nt++) acc[mt][nt] = (float4v)(0.f);

#pragma unroll
    for (int mt = 0; mt < 4; mt++) {
#pragma unroll
        for (int kt = 0; kt < 3; kt++) {
            half8 af = *(const half8*)(w1l +
                ((size_t)(kt * 64 + mt * 16 + lcol) * 32 + q * 8));
#pragma unroll
            for (int nt = 0; nt < 2; nt++)
                acc[mt][nt] = __builtin_amdgcn_mfma_f32_16x16x32_f16(
                    af, bf[nt][kt], acc[mt][nt], 0, 0, 0);
        }
    }

    // ---- gate (lane-local o <-> o+32 pairing), write to wave-private LDS ----
#pragma unroll
    for (int pp = 0; pp < 2; pp++)
#pragma unroll
        for (int nt = 0; nt < 2; nt++) {
            half4 gh;
#pragma unroll
            for (int r = 0; r < 4; r++) {
                float a0 = acc[pp][nt][r];
                float a1 = acc[pp + 2][nt][r];
                gh[r] = (_Float16)(fast_tanh(a0) * fast_sigmoid(a1));
            }
            *(half4*)&Gs[wv][nt * 16 + lcol][pp * 16 + q * 4] = gh;
        }
    // cross-lane within wave: pin compiler ordering (HW DS ops in-order/wave)
    __builtin_amdgcn_wave_barrier();

    // ---- skip prefetch (half4; latency hides under GEMM2) ----
    const int tcol = t0 + n0;
    half4 skv[2][2];
    if (!FIRST) {
#pragma unroll
        for (int mt = 0; mt < 2; mt++)
#pragma unroll
            for (int nt = 0; nt < 2; nt++) {
                int t = tcol + nt * 16 + lcol;
                skv[mt][nt] = *(const half4*)(skip +
                    ((size_t)b * T + t) * SKIPC + mt * 16 + q * 4);
            }
    }

    // ---- GEMM2: 1x1 ----
    float4v zacc[4][2];
#pragma unroll
    for (int mt = 0; mt < 4; mt++)
#pragma unroll
        for (int nt = 0; nt < 2; nt++) zacc[mt][nt] = (float4v)(0.f);

    half8 gb[2];
#pragma unroll
    for (int nt = 0; nt < 2; nt++)
        gb[nt] = *(const half8*)&Gs[wv][nt * 16 + lcol][q * 8];

#pragma unroll
    for (int mt = 0; mt < 4; mt++) {
        half8 af = *(const half8*)(w2l + ((size_t)(mt * 16 + lcol) * 32 + q * 8));
#pragma unroll
        for (int nt = 0; nt < 2; nt++)
            zacc[mt][nt] = __builtin_amdgcn_mfma_f32_16x16x32_f16(
                af, gb[nt], zacc[mt][nt], 0, 0, 0);
    }

    // ---- epilogue ----
#pragma unroll
    for (int mt = 0; mt < 2; mt++)
#pragma unroll
        for (int nt = 0; nt < 2; nt++) {
            int t = tcol + nt * 16 + lcol;
            size_t off = ((size_t)b * T + t) * RES + mt * 16 + q * 4;
            half4 hv = *(const half4*)(h_in + off);
            half4 hw;
#pragma unroll
            for (int r = 0; r < 4; r++)
                hw[r] = (_Float16)((float)hv[r] + zacc[mt][nt][r]);
            *(half4*)(h_out + off) = hw;
        }
#pragma unroll
    for (int mt = 0; mt < 2; mt++)
#pragma unroll
        for (int nt = 0; nt < 2; nt++) {
            int t = tcol + nt * 16 + lcol;
            size_t off = ((size_t)b * T + t) * SKIPC + mt * 16 + q * 4;
            half4 sw;
#pragma unroll
            for (int r = 0; r < 4; r++) {
                float z = zacc[mt + 2][nt][r];
                sw[r] = (_Float16)(FIRST ? z : (float)skv[mt][nt][r] + z);
            }
            *(half4*)(skip + off) = sw;
        }
}

// ---------------- post2: tanh(skip fp16 [B][T][32]) -> conv 32->16 k3 -> tanh
#define P2_TILE 256
__global__ __launch_bounds__(256) void post2_kernel(
        const _Float16* __restrict__ skip,
        const float* __restrict__ w,    // [16][32][3]
        float* __restrict__ out16) {
    __shared__ float st[(P2_TILE + 2) * 33];   // rows t0-2..t0+255, stride 33

    const int tid = threadIdx.x;
    const int t0 = blockIdx.x * P2_TILE;
    const int b = blockIdx.y;

    const int total8 = ((P2_TILE + 2) * 32) / 8;   // 1032 half8 chunks
    for (int ci = tid; ci < total8; ci += 256) {
        int flat = ci * 8;
        int row = flat >> 5;
        int c = flat & 31;
        int ts = t0 - 2 + row;
        half8 v = (half8)(_Float16)0.f;
        if (ts >= 0)
            v = *(const half8*)(skip + ((size_t)b * T + ts) * SKIPC + c);
        float* dst = &st[row * 33 + c];
#pragma unroll
        for (int r = 0; r < 8; r++)
            dst[r] = fast_tanh((float)v[r]);
    }
    __syncthreads();

    const int t = t0 + tid;
    float acc[16];
#pragma unroll
    for (int o = 0; o < 16; o++) acc[o] = 0.f;
#pragma unroll 4
    for (int c = 0; c < 32; c++) {
        float s0 = st[(tid + 0) * 33 + c];   // t-2
        float s1 = st[(tid + 1) * 33 + c];   // t-1
        float s2 = st[(tid + 2) * 33 + c];   // t
#pragma unroll
        for (int o = 0; o < 16; o++) {
            const float* wo = w + (o * 32 + c) * 3;
            acc[o] += wo[0] * s0 + wo[1] * s1 + wo[2] * s2;
        }
    }
#pragma unroll
    for (int o = 0; o < 16; o++)
        out16[((size_t)(b * 16 + o)) * T + t] = fast_tanh(acc[o]);
}

// ---------------- post3: conv 16->8 k3 -> tanh ----------------
__global__ void post3_kernel(const float* __restrict__ in16,
                             const float* __restrict__ w,    // [8][16][3]
                             float* __restrict__ out8) {
    int t = blockIdx.x * blockDim.x + threadIdx.x;
    int b = blockIdx.y;
    float acc[8];
#pragma unroll
    for (int o = 0; o < 8; o++) acc[o] = 0.f;
    for (int c = 0; c < 16; c++) {
        const float* sc = in16 + ((size_t)(b * 16 + c)) * T;
        float v2 = sc[t];
        float v1 = (t >= 1) ? sc[t - 1] : 0.f;
        float v0 = (t >= 2) ? sc[t - 2] : 0.f;
#pragma unroll
        for (int o = 0; o < 8; o++) {
            const float* wo = w + (o * 16 + c) * 3;
            acc[o] += wo[0] * v0 + wo[1] * v1 + wo[2] * v2;
        }
    }
#pragma unroll
    for (int o = 0; o < 8; o++)
        out8[((size_t)(b * 8 + o)) * T + t] = fast_tanh(acc[o]);
}

// ---------------- post4 + vnn fused ----------------
// out1 staged in LDS with 15-col halo (vnn needs out1[t-15..t]); kills the
// out1 HBM round-trip and one launch. Block tile = 256 cols.
__global__ __launch_bounds__(256) void post4_vnn_kernel(
        const float* __restrict__ in8,   // [B][8][T]
        const float* __restrict__ w4,    // [1][8][3]
        const float* __restrict__ w1,    // [1][1][16]
        const float* __restrict__ w2,    // [6][1][16]
        float* __restrict__ out) {       // [B][T]
    __shared__ float s1[272];            // out1 for cols t0-15 .. t0+255

    const int tid = threadIdx.x;
    const int t0 = blockIdx.x * 256;
    const int b = blockIdx.y;

    for (int i = tid; i < 271; i += 256) {
        int c = t0 - 15 + i;
        float o1 = 0.f;
        if (c >= 0) {
            float acc = 0.f;
#pragma unroll
            for (int ch = 0; ch < 8; ch++) {
                const float* sc = in8 + ((size_t)(b * 8 + ch)) * T;
                float v2 = sc[c];
                float v1 = (c >= 1) ? sc[c - 1] : 0.f;
                float v0 = (c >= 2) ? sc[c - 2] : 0.f;
                const float* wo = w4 + ch * 3;
                acc += wo[0] * v0 + wo[1] * v1 + wo[2] * v2;
            }
            o1 = fast_tanh(acc);
        }
        s1[i] = o1;
    }
    __syncthreads();

    const int t = t0 + tid;
    float lin = 0.f;
    float s[6];
#pragma unroll
    for (int qq = 0; qq < 6; qq++) s[qq] = 0.f;
#pragma unroll
    for (int k = 0; k < 16; k++) {
        float tap = s1[tid + k];         // col t-15+k
        lin += w1[k] * tap;
#pragma unroll
        for (int qq = 0; qq < 6; qq++) s[qq] += w2[qq * 16 + k] * tap;
    }
    float quad = s[0] * s[3] + s[1] * s[4] + s[2] * s[5];
    out[(size_t)b * T + t] = lin + quad;
}

extern "C" void kernel_launch(void* const* d_in, const int* in_sizes, int n_in,
                              void* d_out, int out_size, void* d_ws, size_t ws_size,
                              hipStream_t stream) {
    const float* x       = (const float*)d_in[0];
    const float* conv1_w = (const float*)d_in[1];
    const float* res_w1  = (const float*)d_in[2];
    const float* res_w2  = (const float*)d_in[3];
    const float* post2_w = (const float*)d_in[4];
    const float* post3_w = (const float*)d_in[5];
    const float* post4_w = (const float*)d_in[6];
    const float* vnn1_w  = (const float*)d_in[7];
    const float* vnn2_w  = (const float*)d_in[8];
    float* out = (float*)d_out;

    char* ws = (char*)d_ws;
    const size_t SZ_HF   = (size_t)B * RES * T * 2;     // fp16 h buffers
    const size_t SZ_SKIP = (size_t)B * SKIPC * T * 2;   // fp16 skip
    const size_t SZ_O16  = (size_t)B * 16 * T * 4;
    const size_t SZ_O8   = (size_t)B * 8 * T * 4;
    _Float16*  hA    = (_Float16*)(ws);
    _Float16*  hB    = (_Float16*)(ws + SZ_HF);
    _Float16*  skip  = (_Float16*)(ws + 2 * SZ_HF);
    float*     out16 = (float*)(ws + 2 * SZ_HF + SZ_SKIP);
    float*     out8  = (float*)(ws + 2 * SZ_HF + SZ_SKIP + SZ_O16);
    _Float16*  w1f   = (_Float16*)(ws + 2 * SZ_HF + SZ_SKIP + SZ_O16 + SZ_O8);
    _Float16*  w2f   = (_Float16*)(ws + 2 * SZ_HF + SZ_SKIP + SZ_O16 + SZ_O8
                                      + (size_t)NDIL * 3 * 64 * 32 * 2);

    dim3 blk(256);
    dim3 grd(T / 256, B);     // conv1/post3/post4_vnn: 125 x 8
    dim3 grdR(T / 128, B);    // res layers: 250 x 8

    repack_weights_f16<<<dim3((NDIL * 3 * 64 * 32 + 255) / 256), blk, 0, stream>>>(
        res_w1, res_w2, w1f, w2f);

    conv1_kernel<<<grd, blk, 0, stream>>>(x, conv1_w, hA);

    const _Float16* cur = hA;
    _Float16* nxt = hB;
    for (int l = 0; l < NLAYERS; l++) {
        int i = l % NDIL;
        int d = 1 << i;
        const _Float16* w1l = w1f + (size_t)i * 3 * 64 * 32;
        const _Float16* w2l = w2f + (size_t)i * 64 * 32;
        if (l == 0)
            res_layer_mfma<true><<<grdR, blk, 0, stream>>>(cur, nxt, skip, w1l, w2l, d);
        else
            res_layer_mfma<false><<<grdR, blk, 0, stream>>>(cur, nxt, skip, w1l, w2l, d);
        const _Float16* tmp = nxt;
        nxt = (_Float16*)cur;
        cur = tmp;
    }

    post2_kernel<<<dim3(T / P2_TILE, B), blk, 0, stream>>>(skip, post2_w, out16);
    post3_kernel<<<grd, blk, 0, stream>>>(out16, post3_w, out8);
    post4_vnn_kernel<<<grd, blk, 0, stream>>>(out8, post4_w, vnn1_w, vnn2_w, out);
}

// Round 16
// 529.803 us; speedup vs baseline: 1.0816x; 1.0816x over previous
//
#include <hip/hip_runtime.h>
#include <math.h>

#define T 32000
#define B 8
#define RES 32
#define SKIPC 32
#define NDIL 10
#define NLAYERS 20

typedef __attribute__((ext_vector_type(8))) _Float16 half8;
typedef __attribute__((ext_vector_type(4))) _Float16 half4;
typedef __attribute__((ext_vector_type(4))) float float4v;

// ---------------- fast transcendentals ----------------
__device__ __forceinline__ float fast_rcp(float x) { return __builtin_amdgcn_rcpf(x); }
__device__ __forceinline__ float fast_exp2(float x) { return __builtin_amdgcn_exp2f(x); }
__device__ __forceinline__ float fast_sigmoid(float x) {
    return fast_rcp(1.f + fast_exp2(-1.4426950408889634f * x));
}
__device__ __forceinline__ float fast_tanh(float x) {
    return 1.f - 2.f * fast_rcp(1.f + fast_exp2(2.8853900817779268f * x));
}

// ---------------- weight repack to fp16 ----------------
// res_w1: [10][64][32][3] -> w1f: [10][3][64][32] fp16  (tap-major, c contig)
// res_w2: [10][64][32]    -> w2f: [10][64][32] fp16
__global__ void repack_weights_f16(const float* __restrict__ w1,
                                   const float* __restrict__ w2,
                                   _Float16* __restrict__ w1f,
                                   _Float16* __restrict__ w2f) {
    int idx = blockIdx.x * blockDim.x + threadIdx.x;
    if (idx < NDIL * 3 * 64 * 32) {
        int i = idx;
        int c = i % 32; i /= 32;
        int o = i % 64; i /= 64;
        int kt = i % 3; i /= 3;
        int l = i;
        w1f[idx] = (_Float16)w1[((l * 64 + o) * 32 + c) * 3 + kt];
    }
    if (idx < NDIL * 64 * 32) {
        w2f[idx] = (_Float16)w2[idx];
    }
}

// ---------------- conv1: [B,1,T] -> h[B][T][RES] fp16 channel-contiguous ----
__global__ void conv1_kernel(const float* __restrict__ x,
                             const float* __restrict__ w,   // [32][1][3]
                             _Float16* __restrict__ h) {
    int t = blockIdx.x * blockDim.x + threadIdx.x;
    int b = blockIdx.y;
    if (t >= T) return;
    const float* xb = x + (size_t)b * T;
    float x2 = xb[t];
    float x1 = (t >= 1) ? xb[t - 1] : 0.f;
    float x0 = (t >= 2) ? xb[t - 2] : 0.f;
    _Float16* hr = h + ((size_t)b * T + t) * RES;
#pragma unroll
    for (int o = 0; o < RES; o += 8) {
        half8 v;
#pragma unroll
        for (int r = 0; r < 8; r++)
            v[r] = (_Float16)(w[(o + r) * 3 + 0] * x0 + w[(o + r) * 3 + 1] * x1
                            + w[(o + r) * 3 + 2] * x2);
        *(half8*)(hr + o) = v;
    }
}

// ---------------- residual layer via f16 MFMA, fp16 h + fp16 skip -----------
// h fp16 [B][T][32]: B-fragment = ONE 16-byte half8 load. skip fp16.
// G exchange intra-wave via wave-private LDS slab + wave_barrier.
// R16: NO min-waves bound — R15 proved capping VGPR at 64 (8 blk/CU) costs
// more in lost ILP (in-flight loads) than it gains in occupancy. Let the
// compiler take ~80 VGPR and keep all tap/skip loads in flight.
template <bool FIRST>
__global__ __launch_bounds__(256) void res_layer_mfma(
        const _Float16* __restrict__ h_in, _Float16* __restrict__ h_out,
        _Float16* __restrict__ skip,
        const _Float16* __restrict__ w1l,   // [3][64][32] this layer
        const _Float16* __restrict__ w2l,   // [64][32] this layer
        int d) {
    __shared__ _Float16 Gs[4][32][40];      // 10240 B, per-wave slabs

    const int tid = threadIdx.x;
    const int t0 = blockIdx.x * 128;
    const int b = blockIdx.y;
    const int lane = tid & 63;
    const int wv = tid >> 6;
    const int n0 = wv * 32;
    const int lcol = lane & 15;
    const int q = lane >> 4;
    const _Float16* hb = h_in + (size_t)b * T * RES;

    // ---- direct B-frag loads: 6 x one half8 ----
    half8 bf[2][3];
    const half8 zero8 = (half8)(_Float16)0.f;
    if (t0 >= 2 * d) {                      // interior block (uniform branch)
#pragma unroll
        for (int nt = 0; nt < 2; nt++)
#pragma unroll
            for (int kt = 0; kt < 3; kt++) {
                int tb = t0 + n0 + nt * 16 + lcol - (2 - kt) * d;
                bf[nt][kt] = *(const half8*)(hb + (size_t)tb * RES + q * 8);
            }
    } else {
#pragma unroll
        for (int nt = 0; nt < 2; nt++)
#pragma unroll
            for (int kt = 0; kt < 3; kt++) {
                int tb = t0 + n0 + nt * 16 + lcol - (2 - kt) * d;
                bool ok = tb >= 0;
                half8 p = *(const half8*)(hb + (size_t)(ok ? tb : 0) * RES + q * 8);
                bf[nt][kt] = ok ? p : zero8;
            }
    }

    // ---- GEMM1: conv ----
    float4v acc[4][2];
#pragma unroll
    for (int mt = 0; mt < 4; mt++)
#pragma unroll
        for (int nt = 0; nt < 2; nt++) acc[mt][nt] = (float4v)(0.f);

#pragma unroll
    for (int mt = 0; mt < 4; mt++) {
#pragma unroll
        for (int kt = 0; kt < 3; kt++) {
            half8 af = *(const half8*)(w1l +
                ((size_t)(kt * 64 + mt * 16 + lcol) * 32 + q * 8));
#pragma unroll
            for (int nt = 0; nt < 2; nt++)
                acc[mt][nt] = __builtin_amdgcn_mfma_f32_16x16x32_f16(
                    af, bf[nt][kt], acc[mt][nt], 0, 0, 0);
        }
    }

    // ---- gate (lane-local o <-> o+32 pairing), write to wave-private LDS ----
#pragma unroll
    for (int pp = 0; pp < 2; pp++)
#pragma unroll
        for (int nt = 0; nt < 2; nt++) {
            half4 gh;
#pragma unroll
            for (int r = 0; r < 4; r++) {
                float a0 = acc[pp][nt][r];
                float a1 = acc[pp + 2][nt][r];
                gh[r] = (_Float16)(fast_tanh(a0) * fast_sigmoid(a1));
            }
            *(half4*)&Gs[wv][nt * 16 + lcol][pp * 16 + q * 4] = gh;
        }
    // cross-lane within wave: pin compiler ordering (HW DS ops in-order/wave)
    __builtin_amdgcn_wave_barrier();

    // ---- skip prefetch (half4; latency hides under GEMM2) ----
    const int tcol = t0 + n0;
    half4 skv[2][2];
    if (!FIRST) {
#pragma unroll
        for (int mt = 0; mt < 2; mt++)
#pragma unroll
            for (int nt = 0; nt < 2; nt++) {
                int t = tcol + nt * 16 + lcol;
                skv[mt][nt] = *(const half4*)(skip +
                    ((size_t)b * T + t) * SKIPC + mt * 16 + q * 4);
            }
    }

    // ---- GEMM2: 1x1 ----
    float4v zacc[4][2];
#pragma unroll
    for (int mt = 0; mt < 4; mt++)
#pragma unroll
        for (int nt = 0; nt < 2; nt++) zacc[mt][nt] = (float4v)(0.f);

    half8 gb[2];
#pragma unroll
    for (int nt = 0; nt < 2; nt++)
        gb[nt] = *(const half8*)&Gs[wv][nt * 16 + lcol][q * 8];

#pragma unroll
    for (int mt = 0; mt < 4; mt++) {
        half8 af = *(const half8*)(w2l + ((size_t)(mt * 16 + lcol) * 32 + q * 8));
#pragma unroll
        for (int nt = 0; nt < 2; nt++)
            zacc[mt][nt] = __builtin_amdgcn_mfma_f32_16x16x32_f16(
                af, gb[nt], zacc[mt][nt], 0, 0, 0);
    }

    // ---- epilogue ----
#pragma unroll
    for (int mt = 0; mt < 2; mt++)
#pragma unroll
        for (int nt = 0; nt < 2; nt++) {
            int t = tcol + nt * 16 + lcol;
            size_t off = ((size_t)b * T + t) * RES + mt * 16 + q * 4;
            half4 hv = *(const half4*)(h_in + off);
            half4 hw;
#pragma unroll
            for (int r = 0; r < 4; r++)
                hw[r] = (_Float16)((float)hv[r] + zacc[mt][nt][r]);
            *(half4*)(h_out + off) = hw;
        }
#pragma unroll
    for (int mt = 0; mt < 2; mt++)
#pragma unroll
        for (int nt = 0; nt < 2; nt++) {
            int t = tcol + nt * 16 + lcol;
            size_t off = ((size_t)b * T + t) * SKIPC + mt * 16 + q * 4;
            half4 sw;
#pragma unroll
            for (int r = 0; r < 4; r++) {
                float z = zacc[mt + 2][nt][r];
                sw[r] = (_Float16)(FIRST ? z : (float)skv[mt][nt][r] + z);
            }
            *(half4*)(skip + off) = sw;
        }
}

// ---------------- post2: tanh(skip fp16 [B][T][32]) -> conv 32->16 k3 -> tanh
#define P2_TILE 256
__global__ __launch_bounds__(256) void post2_kernel(
        const _Float16* __restrict__ skip,
        const float* __restrict__ w,    // [16][32][3]
        float* __restrict__ out16) {
    __shared__ float st[(P2_TILE + 2) * 33];   // rows t0-2..t0+255, stride 33

    const int tid = threadIdx.x;
    const int t0 = blockIdx.x * P2_TILE;
    const int b = blockIdx.y;

    const int total8 = ((P2_TILE + 2) * 32) / 8;   // 1032 half8 chunks
    for (int ci = tid; ci < total8; ci += 256) {
        int flat = ci * 8;
        int row = flat >> 5;
        int c = flat & 31;
        int ts = t0 - 2 + row;
        half8 v = (half8)(_Float16)0.f;
        if (ts >= 0)
            v = *(const half8*)(skip + ((size_t)b * T + ts) * SKIPC + c);
        float* dst = &st[row * 33 + c];
#pragma unroll
        for (int r = 0; r < 8; r++)
            dst[r] = fast_tanh((float)v[r]);
    }
    __syncthreads();

    const int t = t0 + tid;
    float acc[16];
#pragma unroll
    for (int o = 0; o < 16; o++) acc[o] = 0.f;
#pragma unroll 4
    for (int c = 0; c < 32; c++) {
        float s0 = st[(tid + 0) * 33 + c];   // t-2
        float s1 = st[(tid + 1) * 33 + c];   // t-1
        float s2 = st[(tid + 2) * 33 + c];   // t
#pragma unroll
        for (int o = 0; o < 16; o++) {
            const float* wo = w + (o * 32 + c) * 3;
            acc[o] += wo[0] * s0 + wo[1] * s1 + wo[2] * s2;
        }
    }
#pragma unroll
    for (int o = 0; o < 16; o++)
        out16[((size_t)(b * 16 + o)) * T + t] = fast_tanh(acc[o]);
}

// ---------------- post3: conv 16->8 k3 -> tanh ----------------
__global__ void post3_kernel(const float* __restrict__ in16,
                             const float* __restrict__ w,    // [8][16][3]
                             float* __restrict__ out8) {
    int t = blockIdx.x * blockDim.x + threadIdx.x;
    int b = blockIdx.y;
    float acc[8];
#pragma unroll
    for (int o = 0; o < 8; o++) acc[o] = 0.f;
    for (int c = 0; c < 16; c++) {
        const float* sc = in16 + ((size_t)(b * 16 + c)) * T;
        float v2 = sc[t];
        float v1 = (t >= 1) ? sc[t - 1] : 0.f;
        float v0 = (t >= 2) ? sc[t - 2] : 0.f;
#pragma unroll
        for (int o = 0; o < 8; o++) {
            const float* wo = w + (o * 16 + c) * 3;
            acc[o] += wo[0] * v0 + wo[1] * v1 + wo[2] * v2;
        }
    }
#pragma unroll
    for (int o = 0; o < 8; o++)
        out8[((size_t)(b * 8 + o)) * T + t] = fast_tanh(acc[o]);
}

// ---------------- post4 + vnn fused ----------------
// out1 staged in LDS with 15-col halo (vnn needs out1[t-15..t]); kills the
// out1 HBM round-trip and one launch. Block tile = 256 cols.
__global__ __launch_bounds__(256) void post4_vnn_kernel(
        const float* __restrict__ in8,   // [B][8][T]
        const float* __restrict__ w4,    // [1][8][3]
        const float* __restrict__ w1,    // [1][1][16]
        const float* __restrict__ w2,    // [6][1][16]
        float* __restrict__ out) {       // [B][T]
    __shared__ float s1[272];            // out1 for cols t0-15 .. t0+255

    const int tid = threadIdx.x;
    const int t0 = blockIdx.x * 256;
    const int b = blockIdx.y;

    for (int i = tid; i < 271; i += 256) {
        int c = t0 - 15 + i;
        float o1 = 0.f;
        if (c >= 0) {
            float acc = 0.f;
#pragma unroll
            for (int ch = 0; ch < 8; ch++) {
                const float* sc = in8 + ((size_t)(b * 8 + ch)) * T;
                float v2 = sc[c];
                float v1 = (c >= 1) ? sc[c - 1] : 0.f;
                float v0 = (c >= 2) ? sc[c - 2] : 0.f;
                const float* wo = w4 + ch * 3;
                acc += wo[0] * v0 + wo[1] * v1 + wo[2] * v2;
            }
            o1 = fast_tanh(acc);
        }
        s1[i] = o1;
    }
    __syncthreads();

    const int t = t0 + tid;
    float lin = 0.f;
    float s[6];
#pragma unroll
    for (int qq = 0; qq < 6; qq++) s[qq] = 0.f;
#pragma unroll
    for (int k = 0; k < 16; k++) {
        float tap = s1[tid + k];         // col t-15+k
        lin += w1[k] * tap;
#pragma unroll
        for (int qq = 0; qq < 6; qq++) s[qq] += w2[qq * 16 + k] * tap;
    }
    float quad = s[0] * s[3] + s[1] * s[4] + s[2] * s[5];
    out[(size_t)b * T + t] = lin + quad;
}

extern "C" void kernel_launch(void* const* d_in, const int* in_sizes, int n_in,
                              void* d_out, int out_size, void* d_ws, size_t ws_size,
                              hipStream_t stream) {
    const float* x       = (const float*)d_in[0];
    const float* conv1_w = (const float*)d_in[1];
    const float* res_w1  = (const float*)d_in[2];
    const float* res_w2  = (const float*)d_in[3];
    const float* post2_w = (const float*)d_in[4];
    const float* post3_w = (const float*)d_in[5];
    const float* post4_w = (const float*)d_in[6];
    const float* vnn1_w  = (const float*)d_in[7];
    const float* vnn2_w  = (const float*)d_in[8];
    float* out = (float*)d_out;

    char* ws = (char*)d_ws;
    const size_t SZ_HF   = (size_t)B * RES * T * 2;     // fp16 h buffers
    const size_t SZ_SKIP = (size_t)B * SKIPC * T * 2;   // fp16 skip
    const size_t SZ_O16  = (size_t)B * 16 * T * 4;
    const size_t SZ_O8   = (size_t)B * 8 * T * 4;
    _Float16*  hA    = (_Float16*)(ws);
    _Float16*  hB    = (_Float16*)(ws + SZ_HF);
    _Float16*  skip  = (_Float16*)(ws + 2 * SZ_HF);
    float*     out16 = (float*)(ws + 2 * SZ_HF + SZ_SKIP);
    float*     out8  = (float*)(ws + 2 * SZ_HF + SZ_SKIP + SZ_O16);
    _Float16*  w1f   = (_Float16*)(ws + 2 * SZ_HF + SZ_SKIP + SZ_O16 + SZ_O8);
    _Float16*  w2f   = (_Float16*)(ws + 2 * SZ_HF + SZ_SKIP + SZ_O16 + SZ_O8
                                      + (size_t)NDIL * 3 * 64 * 32 * 2);

    dim3 blk(256);
    dim3 grd(T / 256, B);     // conv1/post3/post4_vnn: 125 x 8
    dim3 grdR(T / 128, B);    // res layers: 250 x 8

    repack_weights_f16<<<dim3((NDIL * 3 * 64 * 32 + 255) / 256), blk, 0, stream>>>(
        res_w1, res_w2, w1f, w2f);

    conv1_kernel<<<grd, blk, 0, stream>>>(x, conv1_w, hA);

    const _Float16* cur = hA;
    _Float16* nxt = hB;
    for (int l = 0; l < NLAYERS; l++) {
        int i = l % NDIL;
        int d = 1 << i;
        const _Float16* w1l = w1f + (size_t)i * 3 * 64 * 32;
        const _Float16* w2l = w2f + (size_t)i * 64 * 32;
        if (l == 0)
            res_layer_mfma<true><<<grdR, blk, 0, stream>>>(cur, nxt, skip, w1l, w2l, d);
        else
            res_layer_mfma<false><<<grdR, blk, 0, stream>>>(cur, nxt, skip, w1l, w2l, d);
        const _Float16* tmp = nxt;
        nxt = (_Float16*)cur;
        cur = tmp;
    }

    post2_kernel<<<dim3(T / P2_TILE, B), blk, 0, stream>>>(skip, post2_w, out16);
    post3_kernel<<<grd, blk, 0, stream>>>(out16, post3_w, out8);
    post4_vnn_kernel<<<grd, blk, 0, stream>>>(out8, post4_w, vnn1_w, vnn2_w, out);
}

// Round 17
// 515.309 us; speedup vs baseline: 1.1121x; 1.0281x over previous
//
#include <hip/hip_runtime.h>
#include <math.h>

#define T 32000
#define B 8
#define RES 32
#define SKIPC 32
#define NDIL 10
#define NLAYERS 20

typedef __attribute__((ext_vector_type(8))) _Float16 half8;
typedef __attribute__((ext_vector_type(4))) _Float16 half4;
typedef __attribute__((ext_vector_type(4))) float float4v;

// ---------------- fast transcendentals ----------------
__device__ __forceinline__ float fast_rcp(float x) { return __builtin_amdgcn_rcpf(x); }
__device__ __forceinline__ float fast_exp2(float x) { return __builtin_amdgcn_exp2f(x); }
__device__ __forceinline__ float fast_sigmoid(float x) {
    return fast_rcp(1.f + fast_exp2(-1.4426950408889634f * x));
}
__device__ __forceinline__ float fast_tanh(float x) {
    return 1.f - 2.f * fast_rcp(1.f + fast_exp2(2.8853900817779268f * x));
}

// ---------------- weight repack to fp16 ----------------
__global__ void repack_weights_f16(const float* __restrict__ w1,
                                   const float* __restrict__ w2,
                                   _Float16* __restrict__ w1f,
                                   _Float16* __restrict__ w2f) {
    int idx = blockIdx.x * blockDim.x + threadIdx.x;
    if (idx < NDIL * 3 * 64 * 32) {
        int i = idx;
        int c = i % 32; i /= 32;
        int o = i % 64; i /= 64;
        int kt = i % 3; i /= 3;
        int l = i;
        w1f[idx] = (_Float16)w1[((l * 64 + o) * 32 + c) * 3 + kt];
    }
    if (idx < NDIL * 64 * 32) {
        w2f[idx] = (_Float16)w2[idx];
    }
}

// ---------------- conv1: [B,1,T] -> h[B][T][RES] fp16 channel-contiguous ----
__global__ void conv1_kernel(const float* __restrict__ x,
                             const float* __restrict__ w,   // [32][1][3]
                             _Float16* __restrict__ h) {
    int t = blockIdx.x * blockDim.x + threadIdx.x;
    int b = blockIdx.y;
    if (t >= T) return;
    const float* xb = x + (size_t)b * T;
    float x2 = xb[t];
    float x1 = (t >= 1) ? xb[t - 1] : 0.f;
    float x0 = (t >= 2) ? xb[t - 2] : 0.f;
    _Float16* hr = h + ((size_t)b * T + t) * RES;
#pragma unroll
    for (int o = 0; o < RES; o += 8) {
        half8 v;
#pragma unroll
        for (int r = 0; r < 8; r++)
            v[r] = (_Float16)(w[(o + r) * 3 + 0] * x0 + w[(o + r) * 3 + 1] * x1
                            + w[(o + r) * 3 + 2] * x2);
        *(half8*)(hr + o) = v;
    }
}

// ---------------- single residual layer (R16 proven) ----------------
template <bool FIRST>
__global__ __launch_bounds__(256) void res_layer_mfma(
        const _Float16* __restrict__ h_in, _Float16* __restrict__ h_out,
        _Float16* __restrict__ skip,
        const _Float16* __restrict__ w1l,   // [3][64][32]
        const _Float16* __restrict__ w2l,   // [64][32]
        int d) {
    __shared__ _Float16 Gs[4][32][40];

    const int tid = threadIdx.x;
    const int t0 = blockIdx.x * 128;
    const int b = blockIdx.y;
    const int lane = tid & 63;
    const int wv = tid >> 6;
    const int n0 = wv * 32;
    const int lcol = lane & 15;
    const int q = lane >> 4;
    const _Float16* hb = h_in + (size_t)b * T * RES;

    half8 bf[2][3];
    const half8 zero8 = (half8)(_Float16)0.f;
    if (t0 >= 2 * d) {
#pragma unroll
        for (int nt = 0; nt < 2; nt++)
#pragma unroll
            for (int kt = 0; kt < 3; kt++) {
                int tb = t0 + n0 + nt * 16 + lcol - (2 - kt) * d;
                bf[nt][kt] = *(const half8*)(hb + (size_t)tb * RES + q * 8);
            }
    } else {
#pragma unroll
        for (int nt = 0; nt < 2; nt++)
#pragma unroll
            for (int kt = 0; kt < 3; kt++) {
                int tb = t0 + n0 + nt * 16 + lcol - (2 - kt) * d;
                bool ok = tb >= 0;
                half8 p = *(const half8*)(hb + (size_t)(ok ? tb : 0) * RES + q * 8);
                bf[nt][kt] = ok ? p : zero8;
            }
    }

    float4v acc[4][2];
#pragma unroll
    for (int mt = 0; mt < 4; mt++)
#pragma unroll
        for (int nt = 0; nt < 2; nt++) acc[mt][nt] = (float4v)(0.f);
#pragma unroll
    for (int mt = 0; mt < 4; mt++)
#pragma unroll
        for (int kt = 0; kt < 3; kt++) {
            half8 af = *(const half8*)(w1l +
                ((size_t)(kt * 64 + mt * 16 + lcol) * 32 + q * 8));
#pragma unroll
            for (int nt = 0; nt < 2; nt++)
                acc[mt][nt] = __builtin_amdgcn_mfma_f32_16x16x32_f16(
                    af, bf[nt][kt], acc[mt][nt], 0, 0, 0);
        }

#pragma unroll
    for (int pp = 0; pp < 2; pp++)
#pragma unroll
        for (int nt = 0; nt < 2; nt++) {
            half4 gh;
#pragma unroll
            for (int r = 0; r < 4; r++)
                gh[r] = (_Float16)(fast_tanh(acc[pp][nt][r]) *
                                   fast_sigmoid(acc[pp + 2][nt][r]));
            *(half4*)&Gs[wv][nt * 16 + lcol][pp * 16 + q * 4] = gh;
        }
    __builtin_amdgcn_wave_barrier();

    const int tcol = t0 + n0;
    half4 skv[2][2];
    if (!FIRST) {
#pragma unroll
        for (int mt = 0; mt < 2; mt++)
#pragma unroll
            for (int nt = 0; nt < 2; nt++) {
                int t = tcol + nt * 16 + lcol;
                skv[mt][nt] = *(const half4*)(skip +
                    ((size_t)b * T + t) * SKIPC + mt * 16 + q * 4);
            }
    }

    float4v zacc[4][2];
#pragma unroll
    for (int mt = 0; mt < 4; mt++)
#pragma unroll
        for (int nt = 0; nt < 2; nt++) zacc[mt][nt] = (float4v)(0.f);
    half8 gb[2];
#pragma unroll
    for (int nt = 0; nt < 2; nt++)
        gb[nt] = *(const half8*)&Gs[wv][nt * 16 + lcol][q * 8];
#pragma unroll
    for (int mt = 0; mt < 4; mt++) {
        half8 af = *(const half8*)(w2l + ((size_t)(mt * 16 + lcol) * 32 + q * 8));
#pragma unroll
        for (int nt = 0; nt < 2; nt++)
            zacc[mt][nt] = __builtin_amdgcn_mfma_f32_16x16x32_f16(
                af, gb[nt], zacc[mt][nt], 0, 0, 0);
    }

#pragma unroll
    for (int mt = 0; mt < 2; mt++)
#pragma unroll
        for (int nt = 0; nt < 2; nt++) {
            int t = tcol + nt * 16 + lcol;
            size_t off = ((size_t)b * T + t) * RES + mt * 16 + q * 4;
            half4 hv = *(const half4*)(h_in + off);
            half4 hw;
#pragma unroll
            for (int r = 0; r < 4; r++)
                hw[r] = (_Float16)((float)hv[r] + zacc[mt][nt][r]);
            *(half4*)(h_out + off) = hw;
        }
#pragma unroll
    for (int mt = 0; mt < 2; mt++)
#pragma unroll
        for (int nt = 0; nt < 2; nt++) {
            int t = tcol + nt * 16 + lcol;
            size_t off = ((size_t)b * T + t) * SKIPC + mt * 16 + q * 4;
            half4 sw;
#pragma unroll
            for (int r = 0; r < 4; r++) {
                float z = zacc[mt + 2][nt][r];
                sw[r] = (_Float16)(FIRST ? z : (float)skv[mt][nt][r] + z);
            }
            *(half4*)(skip + off) = sw;
        }
}

// ---------------- fused layer PAIR (d2 <= 64) ----------------
// Phase A: layer A over [t0-128, t0+128) in two 128-col passes (proven
// structure), h_A -> LDS only (never HBM). Phase B: layer B over core 128
// cols, taps from LDS. ONE skip RMW for both layers (zA+zB). Halo cols'
// skip/h contributions discarded (they are the neighbor block's core).
template <bool FIRST>
__global__ __launch_bounds__(256) void res_pair_mfma(
        const _Float16* __restrict__ h_in, _Float16* __restrict__ h_out,
        _Float16* __restrict__ skip,
        const _Float16* __restrict__ w1A, const _Float16* __restrict__ w2A,
        const _Float16* __restrict__ w1B, const _Float16* __restrict__ w2B,
        int d1, int d2) {
    __shared__ _Float16 hAa[256][40];       // layer-A out, cols t0-128..t0+128
    __shared__ _Float16 Gs[4][32][40];

    const int tid = threadIdx.x;
    const int t0 = blockIdx.x * 128;
    const int b = blockIdx.y;
    const int lane = tid & 63;
    const int wv = tid >> 6;
    const int n0 = wv * 32;
    const int lcol = lane & 15;
    const int q = lane >> 4;
    const _Float16* hb = h_in + (size_t)b * T * RES;
    const half8 zero8 = (half8)(_Float16)0.f;

    float zAs[2][2][4];      // layer-A skip contribution at core cols
    half4 hAcore[2][2];      // layer-A h output at this lane's core cols

    // ===== Phase A =====
#pragma unroll 1
    for (int s = 0; s < 2; s++) {
        const int base = t0 - 128 + s * 128;

        half8 bf[2][3];
        if (base >= 2 * d1) {
#pragma unroll
            for (int nt = 0; nt < 2; nt++)
#pragma unroll
                for (int kt = 0; kt < 3; kt++) {
                    int tb = base + n0 + nt * 16 + lcol - (2 - kt) * d1;
                    bf[nt][kt] = *(const half8*)(hb + (size_t)tb * RES + q * 8);
                }
        } else {
#pragma unroll
            for (int nt = 0; nt < 2; nt++)
#pragma unroll
                for (int kt = 0; kt < 3; kt++) {
                    int tb = base + n0 + nt * 16 + lcol - (2 - kt) * d1;
                    bool ok = tb >= 0;
                    half8 p = *(const half8*)(hb + (size_t)(ok ? tb : 0) * RES + q * 8);
                    bf[nt][kt] = ok ? p : zero8;
                }
        }

        float4v acc[4][2];
#pragma unroll
        for (int mt = 0; mt < 4; mt++)
#pragma unroll
            for (int nt = 0; nt < 2; nt++) acc[mt][nt] = (float4v)(0.f);
#pragma unroll
        for (int mt = 0; mt < 4; mt++)
#pragma unroll
            for (int kt = 0; kt < 3; kt++) {
                half8 af = *(const half8*)(w1A +
                    ((size_t)(kt * 64 + mt * 16 + lcol) * 32 + q * 8));
#pragma unroll
                for (int nt = 0; nt < 2; nt++)
                    acc[mt][nt] = __builtin_amdgcn_mfma_f32_16x16x32_f16(
                        af, bf[nt][kt], acc[mt][nt], 0, 0, 0);
            }

        __builtin_amdgcn_wave_barrier();    // order vs previous pass's Gs reads
#pragma unroll
        for (int pp = 0; pp < 2; pp++)
#pragma unroll
            for (int nt = 0; nt < 2; nt++) {
                half4 gh;
#pragma unroll
                for (int r = 0; r < 4; r++)
                    gh[r] = (_Float16)(fast_tanh(acc[pp][nt][r]) *
                                       fast_sigmoid(acc[pp + 2][nt][r]));
                *(half4*)&Gs[wv][nt * 16 + lcol][pp * 16 + q * 4] = gh;
            }
        __builtin_amdgcn_wave_barrier();

        float4v zacc[4][2];
#pragma unroll
        for (int mt = 0; mt < 4; mt++)
#pragma unroll
            for (int nt = 0; nt < 2; nt++) zacc[mt][nt] = (float4v)(0.f);
        half8 gb[2];
#pragma unroll
        for (int nt = 0; nt < 2; nt++)
            gb[nt] = *(const half8*)&Gs[wv][nt * 16 + lcol][q * 8];
#pragma unroll
        for (int mt = 0; mt < 4; mt++) {
            half8 af = *(const half8*)(w2A + ((size_t)(mt * 16 + lcol) * 32 + q * 8));
#pragma unroll
            for (int nt = 0; nt < 2; nt++)
                zacc[mt][nt] = __builtin_amdgcn_mfma_f32_16x16x32_f16(
                    af, gb[nt], zacc[mt][nt], 0, 0, 0);
        }

        // epilogue: h_A = h_in + z_h -> LDS (zero for t<0)
#pragma unroll
        for (int mt = 0; mt < 2; mt++)
#pragma unroll
            for (int nt = 0; nt < 2; nt++) {
                int t = base + n0 + nt * 16 + lcol;
                bool ok = t >= 0;
                size_t off = ((size_t)b * T + (ok ? t : 0)) * RES + mt * 16 + q * 4;
                half4 hv = *(const half4*)(h_in + off);
                half4 hw;
#pragma unroll
                for (int r = 0; r < 4; r++)
                    hw[r] = ok ? (_Float16)((float)hv[r] + zacc[mt][nt][r])
                               : (_Float16)0.f;
                *(half4*)&hAa[s * 128 + n0 + nt * 16 + lcol][mt * 16 + q * 4] = hw;
                if (s == 1) {
                    hAcore[mt][nt] = hw;
#pragma unroll
                    for (int r = 0; r < 4; r++)
                        zAs[mt][nt][r] = zacc[mt + 2][nt][r];
                }
            }
    }
    __syncthreads();   // hAa visible to all waves

    // ===== Phase B: taps from LDS =====
    half8 bf[2][3];
#pragma unroll
    for (int nt = 0; nt < 2; nt++)
#pragma unroll
        for (int kt = 0; kt < 3; kt++) {
            int rel = 128 + n0 + nt * 16 + lcol - (2 - kt) * d2;  // >= 0 for d2<=64
            bf[nt][kt] = *(const half8*)&hAa[rel][q * 8];
        }

    float4v acc[4][2];
#pragma unroll
    for (int mt = 0; mt < 4; mt++)
#pragma unroll
        for (int nt = 0; nt < 2; nt++) acc[mt][nt] = (float4v)(0.f);
#pragma unroll
    for (int mt = 0; mt < 4; mt++)
#pragma unroll
        for (int kt = 0; kt < 3; kt++) {
            half8 af = *(const half8*)(w1B +
                ((size_t)(kt * 64 + mt * 16 + lcol) * 32 + q * 8));
#pragma unroll
            for (int nt = 0; nt < 2; nt++)
                acc[mt][nt] = __builtin_amdgcn_mfma_f32_16x16x32_f16(
                    af, bf[nt][kt], acc[mt][nt], 0, 0, 0);
        }

    __builtin_amdgcn_wave_barrier();
#pragma unroll
    for (int pp = 0; pp < 2; pp++)
#pragma unroll
        for (int nt = 0; nt < 2; nt++) {
            half4 gh;
#pragma unroll
            for (int r = 0; r < 4; r++)
                gh[r] = (_Float16)(fast_tanh(acc[pp][nt][r]) *
                                   fast_sigmoid(acc[pp + 2][nt][r]));
            *(half4*)&Gs[wv][nt * 16 + lcol][pp * 16 + q * 4] = gh;
        }
    __builtin_amdgcn_wave_barrier();

    const int tcol = t0 + n0;
    half4 skv[2][2];
    if (!FIRST) {
#pragma unroll
        for (int mt = 0; mt < 2; mt++)
#pragma unroll
            for (int nt = 0; nt < 2; nt++) {
                int t = tcol + nt * 16 + lcol;
                skv[mt][nt] = *(const half4*)(skip +
                    ((size_t)b * T + t) * SKIPC + mt * 16 + q * 4);
            }
    }

    float4v zacc[4][2];
#pragma unroll
    for (int mt = 0; mt < 4; mt++)
#pragma unroll
        for (int nt = 0; nt < 2; nt++) zacc[mt][nt] = (float4v)(0.f);
    half8 gb[2];
#pragma unroll
    for (int nt = 0; nt < 2; nt++)
        gb[nt] = *(const half8*)&Gs[wv][nt * 16 + lcol][q * 8];
#pragma unroll
    for (int mt = 0; mt < 4; mt++) {
        half8 af = *(const half8*)(w2B + ((size_t)(mt * 16 + lcol) * 32 + q * 8));
#pragma unroll
        for (int nt = 0; nt < 2; nt++)
            zacc[mt][nt] = __builtin_amdgcn_mfma_f32_16x16x32_f16(
                af, gb[nt], zacc[mt][nt], 0, 0, 0);
    }

    // epilogue: h_out = h_A(core) + zB_h ; skip += zA + zB (single RMW)
#pragma unroll
    for (int mt = 0; mt < 2; mt++)
#pragma unroll
        for (int nt = 0; nt < 2; nt++) {
            int t = tcol + nt * 16 + lcol;
            size_t off = ((size_t)b * T + t) * RES + mt * 16 + q * 4;
            half4 hw;
#pragma unroll
            for (int r = 0; r < 4; r++)
                hw[r] = (_Float16)((float)hAcore[mt][nt][r] + zacc[mt][nt][r]);
            *(half4*)(h_out + off) = hw;
        }
#pragma unroll
    for (int mt = 0; mt < 2; mt++)
#pragma unroll
        for (int nt = 0; nt < 2; nt++) {
            int t = tcol + nt * 16 + lcol;
            size_t off = ((size_t)b * T + t) * SKIPC + mt * 16 + q * 4;
            half4 sw;
#pragma unroll
            for (int r = 0; r < 4; r++) {
                float z = zAs[mt][nt][r] + zacc[mt + 2][nt][r];
                sw[r] = (_Float16)(FIRST ? z : (float)skv[mt][nt][r] + z);
            }
            *(half4*)(skip + off) = sw;
        }
}

// ---------------- post2 ----------------
#define P2_TILE 256
__global__ __launch_bounds__(256) void post2_kernel(
        const _Float16* __restrict__ skip,
        const float* __restrict__ w,    // [16][32][3]
        float* __restrict__ out16) {
    __shared__ float st[(P2_TILE + 2) * 33];

    const int tid = threadIdx.x;
    const int t0 = blockIdx.x * P2_TILE;
    const int b = blockIdx.y;

    const int total8 = ((P2_TILE + 2) * 32) / 8;
    for (int ci = tid; ci < total8; ci += 256) {
        int flat = ci * 8;
        int row = flat >> 5;
        int c = flat & 31;
        int ts = t0 - 2 + row;
        half8 v = (half8)(_Float16)0.f;
        if (ts >= 0)
            v = *(const half8*)(skip + ((size_t)b * T + ts) * SKIPC + c);
        float* dst = &st[row * 33 + c];
#pragma unroll
        for (int r = 0; r < 8; r++)
            dst[r] = fast_tanh((float)v[r]);
    }
    __syncthreads();

    const int t = t0 + tid;
    float acc[16];
#pragma unroll
    for (int o = 0; o < 16; o++) acc[o] = 0.f;
#pragma unroll 4
    for (int c = 0; c < 32; c++) {
        float s0 = st[(tid + 0) * 33 + c];
        float s1 = st[(tid + 1) * 33 + c];
        float s2 = st[(tid + 2) * 33 + c];
#pragma unroll
        for (int o = 0; o < 16; o++) {
            const float* wo = w + (o * 32 + c) * 3;
            acc[o] += wo[0] * s0 + wo[1] * s1 + wo[2] * s2;
        }
    }
#pragma unroll
    for (int o = 0; o < 16; o++)
        out16[((size_t)(b * 16 + o)) * T + t] = fast_tanh(acc[o]);
}

// ---------------- post3 ----------------
__global__ void post3_kernel(const float* __restrict__ in16,
                             const float* __restrict__ w,    // [8][16][3]
                             float* __restrict__ out8) {
    int t = blockIdx.x * blockDim.x + threadIdx.x;
    int b = blockIdx.y;
    float acc[8];
#pragma unroll
    for (int o = 0; o < 8; o++) acc[o] = 0.f;
    for (int c = 0; c < 16; c++) {
        const float* sc = in16 + ((size_t)(b * 16 + c)) * T;
        float v2 = sc[t];
        float v1 = (t >= 1) ? sc[t - 1] : 0.f;
        float v0 = (t >= 2) ? sc[t - 2] : 0.f;
#pragma unroll
        for (int o = 0; o < 8; o++) {
            const float* wo = w + (o * 16 + c) * 3;
            acc[o] += wo[0] * v0 + wo[1] * v1 + wo[2] * v2;
        }
    }
#pragma unroll
    for (int o = 0; o < 8; o++)
        out8[((size_t)(b * 8 + o)) * T + t] = fast_tanh(acc[o]);
}

// ---------------- post4 + vnn fused ----------------
__global__ __launch_bounds__(256) void post4_vnn_kernel(
        const float* __restrict__ in8,   // [B][8][T]
        const float* __restrict__ w4,    // [1][8][3]
        const float* __restrict__ w1,    // [1][1][16]
        const float* __restrict__ w2,    // [6][1][16]
        float* __restrict__ out) {       // [B][T]
    __shared__ float s1[272];

    const int tid = threadIdx.x;
    const int t0 = blockIdx.x * 256;
    const int b = blockIdx.y;

    for (int i = tid; i < 271; i += 256) {
        int c = t0 - 15 + i;
        float o1 = 0.f;
        if (c >= 0) {
            float acc = 0.f;
#pragma unroll
            for (int ch = 0; ch < 8; ch++) {
                const float* sc = in8 + ((size_t)(b * 8 + ch)) * T;
                float v2 = sc[c];
                float v1 = (c >= 1) ? sc[c - 1] : 0.f;
                float v0 = (c >= 2) ? sc[c - 2] : 0.f;
                const float* wo = w4 + ch * 3;
                acc += wo[0] * v0 + wo[1] * v1 + wo[2] * v2;
            }
            o1 = fast_tanh(acc);
        }
        s1[i] = o1;
    }
    __syncthreads();

    const int t = t0 + tid;
    float lin = 0.f;
    float s[6];
#pragma unroll
    for (int qq = 0; qq < 6; qq++) s[qq] = 0.f;
#pragma unroll
    for (int k = 0; k < 16; k++) {
        float tap = s1[tid + k];
        lin += w1[k] * tap;
#pragma unroll
        for (int qq = 0; qq < 6; qq++) s[qq] += w2[qq * 16 + k] * tap;
    }
    float quad = s[0] * s[3] + s[1] * s[4] + s[2] * s[5];
    out[(size_t)b * T + t] = lin + quad;
}

extern "C" void kernel_launch(void* const* d_in, const int* in_sizes, int n_in,
                              void* d_out, int out_size, void* d_ws, size_t ws_size,
                              hipStream_t stream) {
    const float* x       = (const float*)d_in[0];
    const float* conv1_w = (const float*)d_in[1];
    const float* res_w1  = (const float*)d_in[2];
    const float* res_w2  = (const float*)d_in[3];
    const float* post2_w = (const float*)d_in[4];
    const float* post3_w = (const float*)d_in[5];
    const float* post4_w = (const float*)d_in[6];
    const float* vnn1_w  = (const float*)d_in[7];
    const float* vnn2_w  = (const float*)d_in[8];
    float* out = (float*)d_out;

    char* ws = (char*)d_ws;
    const size_t SZ_HF   = (size_t)B * RES * T * 2;
    const size_t SZ_SKIP = (size_t)B * SKIPC * T * 2;
    const size_t SZ_O16  = (size_t)B * 16 * T * 4;
    const size_t SZ_O8   = (size_t)B * 8 * T * 4;
    _Float16*  hA    = (_Float16*)(ws);
    _Float16*  hB    = (_Float16*)(ws + SZ_HF);
    _Float16*  skip  = (_Float16*)(ws + 2 * SZ_HF);
    float*     out16 = (float*)(ws + 2 * SZ_HF + SZ_SKIP);
    float*     out8  = (float*)(ws + 2 * SZ_HF + SZ_SKIP + SZ_O16);
    _Float16*  w1f   = (_Float16*)(ws + 2 * SZ_HF + SZ_SKIP + SZ_O16 + SZ_O8);
    _Float16*  w2f   = (_Float16*)(ws + 2 * SZ_HF + SZ_SKIP + SZ_O16 + SZ_O8
                                      + (size_t)NDIL * 3 * 64 * 32 * 2);

    dim3 blk(256);
    dim3 grd(T / 256, B);
    dim3 grdR(T / 128, B);

    repack_weights_f16<<<dim3((NDIL * 3 * 64 * 32 + 255) / 256), blk, 0, stream>>>(
        res_w1, res_w2, w1f, w2f);

    conv1_kernel<<<grd, blk, 0, stream>>>(x, conv1_w, hA);

    // dispatch plan: fuse pairs where d2 <= 64
    // P(0),P(2),P(4),S(6),S(7),S(8),P(9),P(11),P(13),P(15),S(17),S(18),S(19)
    const int  plan_l[13] = {0, 2, 4, 6, 7, 8, 9, 11, 13, 15, 17, 18, 19};
    const bool plan_p[13] = {true, true, true, false, false, false, true,
                             true, true, true, false, false, false};

    const _Float16* cur = hA;
    _Float16* nxt = hB;
    for (int i = 0; i < 13; i++) {
        int l = plan_l[i];
        int ilA = l % NDIL;
        int d1 = 1 << ilA;
        const _Float16* w1Ap = w1f + (size_t)ilA * 3 * 64 * 32;
        const _Float16* w2Ap = w2f + (size_t)ilA * 64 * 32;
        if (plan_p[i]) {
            int ilB = (l + 1) % NDIL;
            int d2 = 1 << ilB;
            const _Float16* w1Bp = w1f + (size_t)ilB * 3 * 64 * 32;
            const _Float16* w2Bp = w2f + (size_t)ilB * 64 * 32;
            if (i == 0)
                res_pair_mfma<true><<<grdR, blk, 0, stream>>>(
                    cur, nxt, skip, w1Ap, w2Ap, w1Bp, w2Bp, d1, d2);
            else
                res_pair_mfma<false><<<grdR, blk, 0, stream>>>(
                    cur, nxt, skip, w1Ap, w2Ap, w1Bp, w2Bp, d1, d2);
        } else {
            res_layer_mfma<false><<<grdR, blk, 0, stream>>>(
                cur, nxt, skip, w1Ap, w2Ap, d1);
        }
        const _Float16* tmp = nxt;
        nxt = (_Float16*)cur;
        cur = tmp;
    }

    post2_kernel<<<dim3(T / P2_TILE, B), blk, 0, stream>>>(skip, post2_w, out16);
    post3_kernel<<<grd, blk, 0, stream>>>(out16, post3_w, out8);
    post4_vnn_kernel<<<grd, blk, 0, stream>>>(out8, post4_w, vnn1_w, vnn2_w, out);
}

// Round 18
// 503.900 us; speedup vs baseline: 1.1372x; 1.0226x over previous
//
#include <hip/hip_runtime.h>
#include <math.h>

#define T 32000
#define B 8
#define RES 32
#define SKIPC 32
#define NDIL 10
#define NLAYERS 20

typedef __attribute__((ext_vector_type(8))) _Float16 half8;
typedef __attribute__((ext_vector_type(4))) _Float16 half4;
typedef __attribute__((ext_vector_type(4))) float float4v;

// ---------------- fast transcendentals ----------------
__device__ __forceinline__ float fast_rcp(float x) { return __builtin_amdgcn_rcpf(x); }
__device__ __forceinline__ float fast_exp2(float x) { return __builtin_amdgcn_exp2f(x); }
__device__ __forceinline__ float fast_sigmoid(float x) {
    return fast_rcp(1.f + fast_exp2(-1.4426950408889634f * x));
}
__device__ __forceinline__ float fast_tanh(float x) {
    return 1.f - 2.f * fast_rcp(1.f + fast_exp2(2.8853900817779268f * x));
}

// XCD-affine decode: assuming workgroup -> XCD is round-robin on blockIdx.x
// (g % 8), tying batch b = g & 7 keeps each batch's h/skip tiles resident in
// ONE XCD's L2 across all dispatches (taps, residual reload, skip RMW all
// same-XCD). Mapping is a perf heuristic only — correctness unaffected.
__device__ __forceinline__ void decode_bt(int g, int tile, int& b, int& t0) {
    b = g & 7;
    t0 = (g >> 3) * tile;
}

// ---------------- weight repack to fp16 ----------------
__global__ void repack_weights_f16(const float* __restrict__ w1,
                                   const float* __restrict__ w2,
                                   _Float16* __restrict__ w1f,
                                   _Float16* __restrict__ w2f) {
    int idx = blockIdx.x * blockDim.x + threadIdx.x;
    if (idx < NDIL * 3 * 64 * 32) {
        int i = idx;
        int c = i % 32; i /= 32;
        int o = i % 64; i /= 64;
        int kt = i % 3; i /= 3;
        int l = i;
        w1f[idx] = (_Float16)w1[((l * 64 + o) * 32 + c) * 3 + kt];
    }
    if (idx < NDIL * 64 * 32) {
        w2f[idx] = (_Float16)w2[idx];
    }
}

// ---------------- conv1: [B,1,T] -> h[B][T][RES] fp16 channel-contiguous ----
__global__ void conv1_kernel(const float* __restrict__ x,
                             const float* __restrict__ w,   // [32][1][3]
                             _Float16* __restrict__ h) {
    int b, t0;
    decode_bt(blockIdx.x, 256, b, t0);
    int t = t0 + threadIdx.x;
    const float* xb = x + (size_t)b * T;
    float x2 = xb[t];
    float x1 = (t >= 1) ? xb[t - 1] : 0.f;
    float x0 = (t >= 2) ? xb[t - 2] : 0.f;
    _Float16* hr = h + ((size_t)b * T + t) * RES;
#pragma unroll
    for (int o = 0; o < RES; o += 8) {
        half8 v;
#pragma unroll
        for (int r = 0; r < 8; r++)
            v[r] = (_Float16)(w[(o + r) * 3 + 0] * x0 + w[(o + r) * 3 + 1] * x1
                            + w[(o + r) * 3 + 2] * x2);
        *(half8*)(hr + o) = v;
    }
}

// ---------------- single residual layer ----------------
template <bool FIRST>
__global__ __launch_bounds__(256) void res_layer_mfma(
        const _Float16* __restrict__ h_in, _Float16* __restrict__ h_out,
        _Float16* __restrict__ skip,
        const _Float16* __restrict__ w1l,   // [3][64][32]
        const _Float16* __restrict__ w2l,   // [64][32]
        int d) {
    __shared__ _Float16 Gs[4][32][40];

    const int tid = threadIdx.x;
    int b, t0;
    decode_bt(blockIdx.x, 128, b, t0);
    const int lane = tid & 63;
    const int wv = tid >> 6;
    const int n0 = wv * 32;
    const int lcol = lane & 15;
    const int q = lane >> 4;
    const _Float16* hb = h_in + (size_t)b * T * RES;

    half8 bf[2][3];
    const half8 zero8 = (half8)(_Float16)0.f;
    if (t0 >= 2 * d) {
#pragma unroll
        for (int nt = 0; nt < 2; nt++)
#pragma unroll
            for (int kt = 0; kt < 3; kt++) {
                int tb = t0 + n0 + nt * 16 + lcol - (2 - kt) * d;
                bf[nt][kt] = *(const half8*)(hb + (size_t)tb * RES + q * 8);
            }
    } else {
#pragma unroll
        for (int nt = 0; nt < 2; nt++)
#pragma unroll
            for (int kt = 0; kt < 3; kt++) {
                int tb = t0 + n0 + nt * 16 + lcol - (2 - kt) * d;
                bool ok = tb >= 0;
                half8 p = *(const half8*)(hb + (size_t)(ok ? tb : 0) * RES + q * 8);
                bf[nt][kt] = ok ? p : zero8;
            }
    }

    float4v acc[4][2];
#pragma unroll
    for (int mt = 0; mt < 4; mt++)
#pragma unroll
        for (int nt = 0; nt < 2; nt++) acc[mt][nt] = (float4v)(0.f);
#pragma unroll
    for (int mt = 0; mt < 4; mt++)
#pragma unroll
        for (int kt = 0; kt < 3; kt++) {
            half8 af = *(const half8*)(w1l +
                ((size_t)(kt * 64 + mt * 16 + lcol) * 32 + q * 8));
#pragma unroll
            for (int nt = 0; nt < 2; nt++)
                acc[mt][nt] = __builtin_amdgcn_mfma_f32_16x16x32_f16(
                    af, bf[nt][kt], acc[mt][nt], 0, 0, 0);
        }

#pragma unroll
    for (int pp = 0; pp < 2; pp++)
#pragma unroll
        for (int nt = 0; nt < 2; nt++) {
            half4 gh;
#pragma unroll
            for (int r = 0; r < 4; r++)
                gh[r] = (_Float16)(fast_tanh(acc[pp][nt][r]) *
                                   fast_sigmoid(acc[pp + 2][nt][r]));
            *(half4*)&Gs[wv][nt * 16 + lcol][pp * 16 + q * 4] = gh;
        }
    __builtin_amdgcn_wave_barrier();

    const int tcol = t0 + n0;
    half4 skv[2][2];
    if (!FIRST) {
#pragma unroll
        for (int mt = 0; mt < 2; mt++)
#pragma unroll
            for (int nt = 0; nt < 2; nt++) {
                int t = tcol + nt * 16 + lcol;
                skv[mt][nt] = *(const half4*)(skip +
                    ((size_t)b * T + t) * SKIPC + mt * 16 + q * 4);
            }
    }

    float4v zacc[4][2];
#pragma unroll
    for (int mt = 0; mt < 4; mt++)
#pragma unroll
        for (int nt = 0; nt < 2; nt++) zacc[mt][nt] = (float4v)(0.f);
    half8 gb[2];
#pragma unroll
    for (int nt = 0; nt < 2; nt++)
        gb[nt] = *(const half8*)&Gs[wv][nt * 16 + lcol][q * 8];
#pragma unroll
    for (int mt = 0; mt < 4; mt++) {
        half8 af = *(const half8*)(w2l + ((size_t)(mt * 16 + lcol) * 32 + q * 8));
#pragma unroll
        for (int nt = 0; nt < 2; nt++)
            zacc[mt][nt] = __builtin_amdgcn_mfma_f32_16x16x32_f16(
                af, gb[nt], zacc[mt][nt], 0, 0, 0);
    }

#pragma unroll
    for (int mt = 0; mt < 2; mt++)
#pragma unroll
        for (int nt = 0; nt < 2; nt++) {
            int t = tcol + nt * 16 + lcol;
            size_t off = ((size_t)b * T + t) * RES + mt * 16 + q * 4;
            half4 hv = *(const half4*)(h_in + off);
            half4 hw;
#pragma unroll
            for (int r = 0; r < 4; r++)
                hw[r] = (_Float16)((float)hv[r] + zacc[mt][nt][r]);
            *(half4*)(h_out + off) = hw;
        }
#pragma unroll
    for (int mt = 0; mt < 2; mt++)
#pragma unroll
        for (int nt = 0; nt < 2; nt++) {
            int t = tcol + nt * 16 + lcol;
            size_t off = ((size_t)b * T + t) * SKIPC + mt * 16 + q * 4;
            half4 sw;
#pragma unroll
            for (int r = 0; r < 4; r++) {
                float z = zacc[mt + 2][nt][r];
                sw[r] = (_Float16)(FIRST ? z : (float)skv[mt][nt][r] + z);
            }
            *(half4*)(skip + off) = sw;
        }
}

// ---------------- fused layer PAIR (d2 <= 64) ----------------
template <bool FIRST>
__global__ __launch_bounds__(256) void res_pair_mfma(
        const _Float16* __restrict__ h_in, _Float16* __restrict__ h_out,
        _Float16* __restrict__ skip,
        const _Float16* __restrict__ w1A, const _Float16* __restrict__ w2A,
        const _Float16* __restrict__ w1B, const _Float16* __restrict__ w2B,
        int d1, int d2) {
    __shared__ _Float16 hAa[256][40];       // layer-A out, cols t0-128..t0+128
    __shared__ _Float16 Gs[4][32][40];

    const int tid = threadIdx.x;
    int b, t0;
    decode_bt(blockIdx.x, 128, b, t0);
    const int lane = tid & 63;
    const int wv = tid >> 6;
    const int n0 = wv * 32;
    const int lcol = lane & 15;
    const int q = lane >> 4;
    const _Float16* hb = h_in + (size_t)b * T * RES;
    const half8 zero8 = (half8)(_Float16)0.f;

    float zAs[2][2][4];
    half4 hAcore[2][2];

    // ===== Phase A =====
#pragma unroll 1
    for (int s = 0; s < 2; s++) {
        const int base = t0 - 128 + s * 128;

        half8 bf[2][3];
        if (base >= 2 * d1) {
#pragma unroll
            for (int nt = 0; nt < 2; nt++)
#pragma unroll
                for (int kt = 0; kt < 3; kt++) {
                    int tb = base + n0 + nt * 16 + lcol - (2 - kt) * d1;
                    bf[nt][kt] = *(const half8*)(hb + (size_t)tb * RES + q * 8);
                }
        } else {
#pragma unroll
            for (int nt = 0; nt < 2; nt++)
#pragma unroll
                for (int kt = 0; kt < 3; kt++) {
                    int tb = base + n0 + nt * 16 + lcol - (2 - kt) * d1;
                    bool ok = tb >= 0;
                    half8 p = *(const half8*)(hb + (size_t)(ok ? tb : 0) * RES + q * 8);
                    bf[nt][kt] = ok ? p : zero8;
                }
        }

        float4v acc[4][2];
#pragma unroll
        for (int mt = 0; mt < 4; mt++)
#pragma unroll
            for (int nt = 0; nt < 2; nt++) acc[mt][nt] = (float4v)(0.f);
#pragma unroll
        for (int mt = 0; mt < 4; mt++)
#pragma unroll
            for (int kt = 0; kt < 3; kt++) {
                half8 af = *(const half8*)(w1A +
                    ((size_t)(kt * 64 + mt * 16 + lcol) * 32 + q * 8));
#pragma unroll
                for (int nt = 0; nt < 2; nt++)
                    acc[mt][nt] = __builtin_amdgcn_mfma_f32_16x16x32_f16(
                        af, bf[nt][kt], acc[mt][nt], 0, 0, 0);
            }

        __builtin_amdgcn_wave_barrier();
#pragma unroll
        for (int pp = 0; pp < 2; pp++)
#pragma unroll
            for (int nt = 0; nt < 2; nt++) {
                half4 gh;
#pragma unroll
                for (int r = 0; r < 4; r++)
                    gh[r] = (_Float16)(fast_tanh(acc[pp][nt][r]) *
                                       fast_sigmoid(acc[pp + 2][nt][r]));
                *(half4*)&Gs[wv][nt * 16 + lcol][pp * 16 + q * 4] = gh;
            }
        __builtin_amdgcn_wave_barrier();

        float4v zacc[4][2];
#pragma unroll
        for (int mt = 0; mt < 4; mt++)
#pragma unroll
            for (int nt = 0; nt < 2; nt++) zacc[mt][nt] = (float4v)(0.f);
        half8 gb[2];
#pragma unroll
        for (int nt = 0; nt < 2; nt++)
            gb[nt] = *(const half8*)&Gs[wv][nt * 16 + lcol][q * 8];
#pragma unroll
        for (int mt = 0; mt < 4; mt++) {
            half8 af = *(const half8*)(w2A + ((size_t)(mt * 16 + lcol) * 32 + q * 8));
#pragma unroll
            for (int nt = 0; nt < 2; nt++)
                zacc[mt][nt] = __builtin_amdgcn_mfma_f32_16x16x32_f16(
                    af, gb[nt], zacc[mt][nt], 0, 0, 0);
        }

#pragma unroll
        for (int mt = 0; mt < 2; mt++)
#pragma unroll
            for (int nt = 0; nt < 2; nt++) {
                int t = base + n0 + nt * 16 + lcol;
                bool ok = t >= 0;
                size_t off = ((size_t)b * T + (ok ? t : 0)) * RES + mt * 16 + q * 4;
                half4 hv = *(const half4*)(h_in + off);
                half4 hw;
#pragma unroll
                for (int r = 0; r < 4; r++)
                    hw[r] = ok ? (_Float16)((float)hv[r] + zacc[mt][nt][r])
                               : (_Float16)0.f;
                *(half4*)&hAa[s * 128 + n0 + nt * 16 + lcol][mt * 16 + q * 4] = hw;
                if (s == 1) {
                    hAcore[mt][nt] = hw;
#pragma unroll
                    for (int r = 0; r < 4; r++)
                        zAs[mt][nt][r] = zacc[mt + 2][nt][r];
                }
            }
    }
    __syncthreads();

    // ===== Phase B =====
    half8 bf[2][3];
#pragma unroll
    for (int nt = 0; nt < 2; nt++)
#pragma unroll
        for (int kt = 0; kt < 3; kt++) {
            int rel = 128 + n0 + nt * 16 + lcol - (2 - kt) * d2;
            bf[nt][kt] = *(const half8*)&hAa[rel][q * 8];
        }

    float4v acc[4][2];
#pragma unroll
    for (int mt = 0; mt < 4; mt++)
#pragma unroll
        for (int nt = 0; nt < 2; nt++) acc[mt][nt] = (float4v)(0.f);
#pragma unroll
    for (int mt = 0; mt < 4; mt++)
#pragma unroll
        for (int kt = 0; kt < 3; kt++) {
            half8 af = *(const half8*)(w1B +
                ((size_t)(kt * 64 + mt * 16 + lcol) * 32 + q * 8));
#pragma unroll
            for (int nt = 0; nt < 2; nt++)
                acc[mt][nt] = __builtin_amdgcn_mfma_f32_16x16x32_f16(
                    af, bf[nt][kt], acc[mt][nt], 0, 0, 0);
        }

    __builtin_amdgcn_wave_barrier();
#pragma unroll
    for (int pp = 0; pp < 2; pp++)
#pragma unroll
        for (int nt = 0; nt < 2; nt++) {
            half4 gh;
#pragma unroll
            for (int r = 0; r < 4; r++)
                gh[r] = (_Float16)(fast_tanh(acc[pp][nt][r]) *
                                   fast_sigmoid(acc[pp + 2][nt][r]));
            *(half4*)&Gs[wv][nt * 16 + lcol][pp * 16 + q * 4] = gh;
        }
    __builtin_amdgcn_wave_barrier();

    const int tcol = t0 + n0;
    half4 skv[2][2];
    if (!FIRST) {
#pragma unroll
        for (int mt = 0; mt < 2; mt++)
#pragma unroll
            for (int nt = 0; nt < 2; nt++) {
                int t = tcol + nt * 16 + lcol;
                skv[mt][nt] = *(const half4*)(skip +
                    ((size_t)b * T + t) * SKIPC + mt * 16 + q * 4);
            }
    }

    float4v zacc[4][2];
#pragma unroll
    for (int mt = 0; mt < 4; mt++)
#pragma unroll
        for (int nt = 0; nt < 2; nt++) zacc[mt][nt] = (float4v)(0.f);
    half8 gb[2];
#pragma unroll
    for (int nt = 0; nt < 2; nt++)
        gb[nt] = *(const half8*)&Gs[wv][nt * 16 + lcol][q * 8];
#pragma unroll
    for (int mt = 0; mt < 4; mt++) {
        half8 af = *(const half8*)(w2B + ((size_t)(mt * 16 + lcol) * 32 + q * 8));
#pragma unroll
        for (int nt = 0; nt < 2; nt++)
            zacc[mt][nt] = __builtin_amdgcn_mfma_f32_16x16x32_f16(
                af, gb[nt], zacc[mt][nt], 0, 0, 0);
    }

#pragma unroll
    for (int mt = 0; mt < 2; mt++)
#pragma unroll
        for (int nt = 0; nt < 2; nt++) {
            int t = tcol + nt * 16 + lcol;
            size_t off = ((size_t)b * T + t) * RES + mt * 16 + q * 4;
            half4 hw;
#pragma unroll
            for (int r = 0; r < 4; r++)
                hw[r] = (_Float16)((float)hAcore[mt][nt][r] + zacc[mt][nt][r]);
            *(half4*)(h_out + off) = hw;
        }
#pragma unroll
    for (int mt = 0; mt < 2; mt++)
#pragma unroll
        for (int nt = 0; nt < 2; nt++) {
            int t = tcol + nt * 16 + lcol;
            size_t off = ((size_t)b * T + t) * SKIPC + mt * 16 + q * 4;
            half4 sw;
#pragma unroll
            for (int r = 0; r < 4; r++) {
                float z = zAs[mt][nt][r] + zacc[mt + 2][nt][r];
                sw[r] = (_Float16)(FIRST ? z : (float)skv[mt][nt][r] + z);
            }
            *(half4*)(skip + off) = sw;
        }
}

// ---------------- post2 ----------------
#define P2_TILE 256
__global__ __launch_bounds__(256) void post2_kernel(
        const _Float16* __restrict__ skip,
        const float* __restrict__ w,    // [16][32][3]
        float* __restrict__ out16) {
    __shared__ float st[(P2_TILE + 2) * 33];

    const int tid = threadIdx.x;
    int b, t0;
    decode_bt(blockIdx.x, P2_TILE, b, t0);

    const int total8 = ((P2_TILE + 2) * 32) / 8;
    for (int ci = tid; ci < total8; ci += 256) {
        int flat = ci * 8;
        int row = flat >> 5;
        int c = flat & 31;
        int ts = t0 - 2 + row;
        half8 v = (half8)(_Float16)0.f;
        if (ts >= 0)
            v = *(const half8*)(skip + ((size_t)b * T + ts) * SKIPC + c);
        float* dst = &st[row * 33 + c];
#pragma unroll
        for (int r = 0; r < 8; r++)
            dst[r] = fast_tanh((float)v[r]);
    }
    __syncthreads();

    const int t = t0 + tid;
    float acc[16];
#pragma unroll
    for (int o = 0; o < 16; o++) acc[o] = 0.f;
#pragma unroll 4
    for (int c = 0; c < 32; c++) {
        float s0 = st[(tid + 0) * 33 + c];
        float s1 = st[(tid + 1) * 33 + c];
        float s2 = st[(tid + 2) * 33 + c];
#pragma unroll
        for (int o = 0; o < 16; o++) {
            const float* wo = w + (o * 32 + c) * 3;
            acc[o] += wo[0] * s0 + wo[1] * s1 + wo[2] * s2;
        }
    }
#pragma unroll
    for (int o = 0; o < 16; o++)
        out16[((size_t)(b * 16 + o)) * T + t] = fast_tanh(acc[o]);
}

// ---------------- post3 ----------------
__global__ void post3_kernel(const float* __restrict__ in16,
                             const float* __restrict__ w,    // [8][16][3]
                             float* __restrict__ out8) {
    int b, t0;
    decode_bt(blockIdx.x, 256, b, t0);
    int t = t0 + threadIdx.x;
    float acc[8];
#pragma unroll
    for (int o = 0; o < 8; o++) acc[o] = 0.f;
    for (int c = 0; c < 16; c++) {
        const float* sc = in16 + ((size_t)(b * 16 + c)) * T;
        float v2 = sc[t];
        float v1 = (t >= 1) ? sc[t - 1] : 0.f;
        float v0 = (t >= 2) ? sc[t - 2] : 0.f;
#pragma unroll
        for (int o = 0; o < 8; o++) {
            const float* wo = w + (o * 16 + c) * 3;
            acc[o] += wo[0] * v0 + wo[1] * v1 + wo[2] * v2;
        }
    }
#pragma unroll
    for (int o = 0; o < 8; o++)
        out8[((size_t)(b * 8 + o)) * T + t] = fast_tanh(acc[o]);
}

// ---------------- post4 + vnn fused ----------------
__global__ __launch_bounds__(256) void post4_vnn_kernel(
        const float* __restrict__ in8,   // [B][8][T]
        const float* __restrict__ w4,    // [1][8][3]
        const float* __restrict__ w1,    // [1][1][16]
        const float* __restrict__ w2,    // [6][1][16]
        float* __restrict__ out) {       // [B][T]
    __shared__ float s1[272];

    const int tid = threadIdx.x;
    int b, t0;
    decode_bt(blockIdx.x, 256, b, t0);

    for (int i = tid; i < 271; i += 256) {
        int c = t0 - 15 + i;
        float o1 = 0.f;
        if (c >= 0) {
            float acc = 0.f;
#pragma unroll
            for (int ch = 0; ch < 8; ch++) {
                const float* sc = in8 + ((size_t)(b * 8 + ch)) * T;
                float v2 = sc[c];
                float v1 = (c >= 1) ? sc[c - 1] : 0.f;
                float v0 = (c >= 2) ? sc[c - 2] : 0.f;
                const float* wo = w4 + ch * 3;
                acc += wo[0] * v0 + wo[1] * v1 + wo[2] * v2;
            }
            o1 = fast_tanh(acc);
        }
        s1[i] = o1;
    }
    __syncthreads();

    const int t = t0 + tid;
    float lin = 0.f;
    float s[6];
#pragma unroll
    for (int qq = 0; qq < 6; qq++) s[qq] = 0.f;
#pragma unroll
    for (int k = 0; k < 16; k++) {
        float tap = s1[tid + k];
        lin += w1[k] * tap;
#pragma unroll
        for (int qq = 0; qq < 6; qq++) s[qq] += w2[qq * 16 + k] * tap;
    }
    float quad = s[0] * s[3] + s[1] * s[4] + s[2] * s[5];
    out[(size_t)b * T + t] = lin + quad;
}

extern "C" void kernel_launch(void* const* d_in, const int* in_sizes, int n_in,
                              void* d_out, int out_size, void* d_ws, size_t ws_size,
                              hipStream_t stream) {
    const float* x       = (const float*)d_in[0];
    const float* conv1_w = (const float*)d_in[1];
    const float* res_w1  = (const float*)d_in[2];
    const float* res_w2  = (const float*)d_in[3];
    const float* post2_w = (const float*)d_in[4];
    const float* post3_w = (const float*)d_in[5];
    const float* post4_w = (const float*)d_in[6];
    const float* vnn1_w  = (const float*)d_in[7];
    const float* vnn2_w  = (const float*)d_in[8];
    float* out = (float*)d_out;

    char* ws = (char*)d_ws;
    const size_t SZ_HF   = (size_t)B * RES * T * 2;
    const size_t SZ_SKIP = (size_t)B * SKIPC * T * 2;
    const size_t SZ_O16  = (size_t)B * 16 * T * 4;
    const size_t SZ_O8   = (size_t)B * 8 * T * 4;
    _Float16*  hA    = (_Float16*)(ws);
    _Float16*  hB    = (_Float16*)(ws + SZ_HF);
    _Float16*  skip  = (_Float16*)(ws + 2 * SZ_HF);
    float*     out16 = (float*)(ws + 2 * SZ_HF + SZ_SKIP);
    float*     out8  = (float*)(ws + 2 * SZ_HF + SZ_SKIP + SZ_O16);
    _Float16*  w1f   = (_Float16*)(ws + 2 * SZ_HF + SZ_SKIP + SZ_O16 + SZ_O8);
    _Float16*  w2f   = (_Float16*)(ws + 2 * SZ_HF + SZ_SKIP + SZ_O16 + SZ_O8
                                      + (size_t)NDIL * 3 * 64 * 32 * 2);

    dim3 blk(256);
    // 1-D grids so blockIdx.x % 8 (assumed XCD round-robin) == batch index
    dim3 grd(125 * 8);     // conv1/post3/post4_vnn: tile 256
    dim3 grdR(250 * 8);    // res layers: tile 128

    repack_weights_f16<<<dim3((NDIL * 3 * 64 * 32 + 255) / 256), blk, 0, stream>>>(
        res_w1, res_w2, w1f, w2f);

    conv1_kernel<<<grd, blk, 0, stream>>>(x, conv1_w, hA);

    // dispatch plan: fuse pairs where d2 <= 64
    const int  plan_l[13] = {0, 2, 4, 6, 7, 8, 9, 11, 13, 15, 17, 18, 19};
    const bool plan_p[13] = {true, true, true, false, false, false, true,
                             true, true, true, false, false, false};

    const _Float16* cur = hA;
    _Float16* nxt = hB;
    for (int i = 0; i < 13; i++) {
        int l = plan_l[i];
        int ilA = l % NDIL;
        int d1 = 1 << ilA;
        const _Float16* w1Ap = w1f + (size_t)ilA * 3 * 64 * 32;
        const _Float16* w2Ap = w2f + (size_t)ilA * 64 * 32;
        if (plan_p[i]) {
            int ilB = (l + 1) % NDIL;
            int d2 = 1 << ilB;
            const _Float16* w1Bp = w1f + (size_t)ilB * 3 * 64 * 32;
            const _Float16* w2Bp = w2f + (size_t)ilB * 64 * 32;
            if (i == 0)
                res_pair_mfma<true><<<grdR, blk, 0, stream>>>(
                    cur, nxt, skip, w1Ap, w2Ap, w1Bp, w2Bp, d1, d2);
            else
                res_pair_mfma<false><<<grdR, blk, 0, stream>>>(
                    cur, nxt, skip, w1Ap, w2Ap, w1Bp, w2Bp, d1, d2);
        } else {
            res_layer_mfma<false><<<grdR, blk, 0, stream>>>(
                cur, nxt, skip, w1Ap, w2Ap, d1);
        }
        const _Float16* tmp = nxt;
        nxt = (_Float16*)cur;
        cur = tmp;
    }

    post2_kernel<<<grd, blk, 0, stream>>>(skip, post2_w, out16);
    post3_kernel<<<grd, blk, 0, stream>>>(out16, post3_w, out8);
    post4_vnn_kernel<<<grd, blk, 0, stream>>>(out8, post4_w, vnn1_w, vnn2_w, out);
}

// Round 19
// 458.697 us; speedup vs baseline: 1.2493x; 1.0985x over previous
//
#include <hip/hip_runtime.h>
#include <math.h>

#define T 32000
#define B 8
#define RES 32
#define SKIPC 32
#define NDIL 10
#define NLAYERS 20

typedef __attribute__((ext_vector_type(8))) _Float16 half8;
typedef __attribute__((ext_vector_type(4))) _Float16 half4;
typedef __attribute__((ext_vector_type(4))) float float4v;

// ---------------- fast transcendentals ----------------
__device__ __forceinline__ float fast_rcp(float x) { return __builtin_amdgcn_rcpf(x); }
__device__ __forceinline__ float fast_exp2(float x) { return __builtin_amdgcn_exp2f(x); }
__device__ __forceinline__ float fast_sigmoid(float x) {
    return fast_rcp(1.f + fast_exp2(-1.4426950408889634f * x));
}
__device__ __forceinline__ float fast_tanh(float x) {
    return 1.f - 2.f * fast_rcp(1.f + fast_exp2(2.8853900817779268f * x));
}

// XCD-affine decode (R18 win): b = g & 7 pins each batch to one XCD's L2.
__device__ __forceinline__ void decode_bt(int g, int tile, int& b, int& t0) {
    b = g & 7;
    t0 = (g >> 3) * tile;
}

// ---- weight staging into LDS, padded stride 40 halfs (80 B) ----
// Bank-start per lane = (lcol*20 + q*4) % 32 -> only (lcol, lcol+8) collide
// = 2-way = free [m136]. Kills the dominant L2 traffic (R18 audit: weight
// A-frag re-reads were 2.7x tap traffic).
#define WROW 40
__device__ __forceinline__ void stage_w1(const _Float16* __restrict__ w1l,
                                         _Float16* w1s, int tid) {
    for (int i = tid; i < 192 * 4; i += 256) {   // 192 rows x 4 half8 chunks
        int row = i >> 2, c = (i & 3) * 8;
        *(half8*)&w1s[row * WROW + c] = *(const half8*)(w1l + row * 32 + c);
    }
}
__device__ __forceinline__ void stage_w2(const _Float16* __restrict__ w2l,
                                         _Float16* w2s, int tid) {
    for (int i = tid; i < 64 * 4; i += 256) {    // 64 rows x 4 chunks
        int row = i >> 2, c = (i & 3) * 8;
        *(half8*)&w2s[row * WROW + c] = *(const half8*)(w2l + row * 32 + c);
    }
}

// ---------------- weight repack to fp16 ----------------
__global__ void repack_weights_f16(const float* __restrict__ w1,
                                   const float* __restrict__ w2,
                                   _Float16* __restrict__ w1f,
                                   _Float16* __restrict__ w2f) {
    int idx = blockIdx.x * blockDim.x + threadIdx.x;
    if (idx < NDIL * 3 * 64 * 32) {
        int i = idx;
        int c = i % 32; i /= 32;
        int o = i % 64; i /= 64;
        int kt = i % 3; i /= 3;
        int l = i;
        w1f[idx] = (_Float16)w1[((l * 64 + o) * 32 + c) * 3 + kt];
    }
    if (idx < NDIL * 64 * 32) {
        w2f[idx] = (_Float16)w2[idx];
    }
}

// ---------------- conv1: [B,1,T] -> h[B][T][RES] fp16 channel-contiguous ----
__global__ void conv1_kernel(const float* __restrict__ x,
                             const float* __restrict__ w,   // [32][1][3]
                             _Float16* __restrict__ h) {
    int b, t0;
    decode_bt(blockIdx.x, 256, b, t0);
    int t = t0 + threadIdx.x;
    const float* xb = x + (size_t)b * T;
    float x2 = xb[t];
    float x1 = (t >= 1) ? xb[t - 1] : 0.f;
    float x0 = (t >= 2) ? xb[t - 2] : 0.f;
    _Float16* hr = h + ((size_t)b * T + t) * RES;
#pragma unroll
    for (int o = 0; o < RES; o += 8) {
        half8 v;
#pragma unroll
        for (int r = 0; r < 8; r++)
            v[r] = (_Float16)(w[(o + r) * 3 + 0] * x0 + w[(o + r) * 3 + 1] * x1
                            + w[(o + r) * 3 + 2] * x2);
        *(half8*)(hr + o) = v;
    }
}

// ---------------- single residual layer (weights in LDS) ----------------
template <bool FIRST>
__global__ __launch_bounds__(256) void res_layer_mfma(
        const _Float16* __restrict__ h_in, _Float16* __restrict__ h_out,
        _Float16* __restrict__ skip,
        const _Float16* __restrict__ w1l,   // [3][64][32]
        const _Float16* __restrict__ w2l,   // [64][32]
        int d) {
    __shared__ _Float16 Gs[4][32][40];      // 10240 B
    __shared__ _Float16 w1s[192 * WROW];    // 15360 B
    __shared__ _Float16 w2s[64 * WROW];     //  5120 B   (total 30720)

    const int tid = threadIdx.x;
    int b, t0;
    decode_bt(blockIdx.x, 128, b, t0);
    const int lane = tid & 63;
    const int wv = tid >> 6;
    const int n0 = wv * 32;
    const int lcol = lane & 15;
    const int q = lane >> 4;
    const _Float16* hb = h_in + (size_t)b * T * RES;

    stage_w1(w1l, w1s, tid);
    stage_w2(w2l, w2s, tid);

    half8 bf[2][3];
    const half8 zero8 = (half8)(_Float16)0.f;
    if (t0 >= 2 * d) {
#pragma unroll
        for (int nt = 0; nt < 2; nt++)
#pragma unroll
            for (int kt = 0; kt < 3; kt++) {
                int tb = t0 + n0 + nt * 16 + lcol - (2 - kt) * d;
                bf[nt][kt] = *(const half8*)(hb + (size_t)tb * RES + q * 8);
            }
    } else {
#pragma unroll
        for (int nt = 0; nt < 2; nt++)
#pragma unroll
            for (int kt = 0; kt < 3; kt++) {
                int tb = t0 + n0 + nt * 16 + lcol - (2 - kt) * d;
                bool ok = tb >= 0;
                half8 p = *(const half8*)(hb + (size_t)(ok ? tb : 0) * RES + q * 8);
                bf[nt][kt] = ok ? p : zero8;
            }
    }
    __syncthreads();   // weights staged

    float4v acc[4][2];
#pragma unroll
    for (int mt = 0; mt < 4; mt++)
#pragma unroll
        for (int nt = 0; nt < 2; nt++) acc[mt][nt] = (float4v)(0.f);
#pragma unroll
    for (int mt = 0; mt < 4; mt++)
#pragma unroll
        for (int kt = 0; kt < 3; kt++) {
            half8 af = *(const half8*)&w1s[(kt * 64 + mt * 16 + lcol) * WROW + q * 8];
#pragma unroll
            for (int nt = 0; nt < 2; nt++)
                acc[mt][nt] = __builtin_amdgcn_mfma_f32_16x16x32_f16(
                    af, bf[nt][kt], acc[mt][nt], 0, 0, 0);
        }

#pragma unroll
    for (int pp = 0; pp < 2; pp++)
#pragma unroll
        for (int nt = 0; nt < 2; nt++) {
            half4 gh;
#pragma unroll
            for (int r = 0; r < 4; r++)
                gh[r] = (_Float16)(fast_tanh(acc[pp][nt][r]) *
                                   fast_sigmoid(acc[pp + 2][nt][r]));
            *(half4*)&Gs[wv][nt * 16 + lcol][pp * 16 + q * 4] = gh;
        }
    __builtin_amdgcn_wave_barrier();

    const int tcol = t0 + n0;
    half4 skv[2][2];
    if (!FIRST) {
#pragma unroll
        for (int mt = 0; mt < 2; mt++)
#pragma unroll
            for (int nt = 0; nt < 2; nt++) {
                int t = tcol + nt * 16 + lcol;
                skv[mt][nt] = *(const half4*)(skip +
                    ((size_t)b * T + t) * SKIPC + mt * 16 + q * 4);
            }
    }

    float4v zacc[4][2];
#pragma unroll
    for (int mt = 0; mt < 4; mt++)
#pragma unroll
        for (int nt = 0; nt < 2; nt++) zacc[mt][nt] = (float4v)(0.f);
    half8 gb[2];
#pragma unroll
    for (int nt = 0; nt < 2; nt++)
        gb[nt] = *(const half8*)&Gs[wv][nt * 16 + lcol][q * 8];
#pragma unroll
    for (int mt = 0; mt < 4; mt++) {
        half8 af = *(const half8*)&w2s[(mt * 16 + lcol) * WROW + q * 8];
#pragma unroll
        for (int nt = 0; nt < 2; nt++)
            zacc[mt][nt] = __builtin_amdgcn_mfma_f32_16x16x32_f16(
                af, gb[nt], zacc[mt][nt], 0, 0, 0);
    }

#pragma unroll
    for (int mt = 0; mt < 2; mt++)
#pragma unroll
        for (int nt = 0; nt < 2; nt++) {
            int t = tcol + nt * 16 + lcol;
            size_t off = ((size_t)b * T + t) * RES + mt * 16 + q * 4;
            half4 hv = *(const half4*)(h_in + off);
            half4 hw;
#pragma unroll
            for (int r = 0; r < 4; r++)
                hw[r] = (_Float16)((float)hv[r] + zacc[mt][nt][r]);
            *(half4*)(h_out + off) = hw;
        }
#pragma unroll
    for (int mt = 0; mt < 2; mt++)
#pragma unroll
        for (int nt = 0; nt < 2; nt++) {
            int t = tcol + nt * 16 + lcol;
            size_t off = ((size_t)b * T + t) * SKIPC + mt * 16 + q * 4;
            half4 sw;
#pragma unroll
            for (int r = 0; r < 4; r++) {
                float z = zacc[mt + 2][nt][r];
                sw[r] = (_Float16)(FIRST ? z : (float)skv[mt][nt][r] + z);
            }
            *(half4*)(skip + off) = sw;
        }
}

// ---------------- fused layer PAIR (d2 <= 64), weights in LDS ---------------
// Phase A stages w1A/w2A; at the hAa barrier we re-stage w1B/w2B (A-weight
// reads are complete by then). LDS: 20480 + 10240 + 20480 = 51200 B -> 3/CU.
template <bool FIRST>
__global__ __launch_bounds__(256) void res_pair_mfma(
        const _Float16* __restrict__ h_in, _Float16* __restrict__ h_out,
        _Float16* __restrict__ skip,
        const _Float16* __restrict__ w1A, const _Float16* __restrict__ w2A,
        const _Float16* __restrict__ w1B, const _Float16* __restrict__ w2B,
        int d1, int d2) {
    __shared__ _Float16 hAa[256][40];       // 20480 B
    __shared__ _Float16 Gs[4][32][40];      // 10240 B
    __shared__ _Float16 w1s[192 * WROW];    // 15360 B
    __shared__ _Float16 w2s[64 * WROW];     //  5120 B

    const int tid = threadIdx.x;
    int b, t0;
    decode_bt(blockIdx.x, 128, b, t0);
    const int lane = tid & 63;
    const int wv = tid >> 6;
    const int n0 = wv * 32;
    const int lcol = lane & 15;
    const int q = lane >> 4;
    const _Float16* hb = h_in + (size_t)b * T * RES;
    const half8 zero8 = (half8)(_Float16)0.f;

    float zAs[2][2][4];
    half4 hAcore[2][2];

    stage_w1(w1A, w1s, tid);
    stage_w2(w2A, w2s, tid);
    __syncthreads();

    // ===== Phase A =====
#pragma unroll 1
    for (int s = 0; s < 2; s++) {
        const int base = t0 - 128 + s * 128;

        half8 bf[2][3];
        if (base >= 2 * d1) {
#pragma unroll
            for (int nt = 0; nt < 2; nt++)
#pragma unroll
                for (int kt = 0; kt < 3; kt++) {
                    int tb = base + n0 + nt * 16 + lcol - (2 - kt) * d1;
                    bf[nt][kt] = *(const half8*)(hb + (size_t)tb * RES + q * 8);
                }
        } else {
#pragma unroll
            for (int nt = 0; nt < 2; nt++)
#pragma unroll
                for (int kt = 0; kt < 3; kt++) {
                    int tb = base + n0 + nt * 16 + lcol - (2 - kt) * d1;
                    bool ok = tb >= 0;
                    half8 p = *(const half8*)(hb + (size_t)(ok ? tb : 0) * RES + q * 8);
                    bf[nt][kt] = ok ? p : zero8;
                }
        }

        float4v acc[4][2];
#pragma unroll
        for (int mt = 0; mt < 4; mt++)
#pragma unroll
            for (int nt = 0; nt < 2; nt++) acc[mt][nt] = (float4v)(0.f);
#pragma unroll
        for (int mt = 0; mt < 4; mt++)
#pragma unroll
            for (int kt = 0; kt < 3; kt++) {
                half8 af = *(const half8*)&w1s[(kt * 64 + mt * 16 + lcol) * WROW + q * 8];
#pragma unroll
                for (int nt = 0; nt < 2; nt++)
                    acc[mt][nt] = __builtin_amdgcn_mfma_f32_16x16x32_f16(
                        af, bf[nt][kt], acc[mt][nt], 0, 0, 0);
            }

        __builtin_amdgcn_wave_barrier();
#pragma unroll
        for (int pp = 0; pp < 2; pp++)
#pragma unroll
            for (int nt = 0; nt < 2; nt++) {
                half4 gh;
#pragma unroll
                for (int r = 0; r < 4; r++)
                    gh[r] = (_Float16)(fast_tanh(acc[pp][nt][r]) *
                                       fast_sigmoid(acc[pp + 2][nt][r]));
                *(half4*)&Gs[wv][nt * 16 + lcol][pp * 16 + q * 4] = gh;
            }
        __builtin_amdgcn_wave_barrier();

        float4v zacc[4][2];
#pragma unroll
        for (int mt = 0; mt < 4; mt++)
#pragma unroll
            for (int nt = 0; nt < 2; nt++) zacc[mt][nt] = (float4v)(0.f);
        half8 gb[2];
#pragma unroll
        for (int nt = 0; nt < 2; nt++)
            gb[nt] = *(const half8*)&Gs[wv][nt * 16 + lcol][q * 8];
#pragma unroll
        for (int mt = 0; mt < 4; mt++) {
            half8 af = *(const half8*)&w2s[(mt * 16 + lcol) * WROW + q * 8];
#pragma unroll
            for (int nt = 0; nt < 2; nt++)
                zacc[mt][nt] = __builtin_amdgcn_mfma_f32_16x16x32_f16(
                    af, gb[nt], zacc[mt][nt], 0, 0, 0);
        }

#pragma unroll
        for (int mt = 0; mt < 2; mt++)
#pragma unroll
            for (int nt = 0; nt < 2; nt++) {
                int t = base + n0 + nt * 16 + lcol;
                bool ok = t >= 0;
                size_t off = ((size_t)b * T + (ok ? t : 0)) * RES + mt * 16 + q * 4;
                half4 hv = *(const half4*)(h_in + off);
                half4 hw;
#pragma unroll
                for (int r = 0; r < 4; r++)
                    hw[r] = ok ? (_Float16)((float)hv[r] + zacc[mt][nt][r])
                               : (_Float16)0.f;
                *(half4*)&hAa[s * 128 + n0 + nt * 16 + lcol][mt * 16 + q * 4] = hw;
                if (s == 1) {
                    hAcore[mt][nt] = hw;
#pragma unroll
                    for (int r = 0; r < 4; r++)
                        zAs[mt][nt][r] = zacc[mt + 2][nt][r];
                }
            }
    }
    __syncthreads();   // hAa visible; all A-weight reads complete

    stage_w1(w1B, w1s, tid);
    stage_w2(w2B, w2s, tid);
    __syncthreads();   // B weights staged

    // ===== Phase B =====
    half8 bf[2][3];
#pragma unroll
    for (int nt = 0; nt < 2; nt++)
#pragma unroll
        for (int kt = 0; kt < 3; kt++) {
            int rel = 128 + n0 + nt * 16 + lcol - (2 - kt) * d2;
            bf[nt][kt] = *(const half8*)&hAa[rel][q * 8];
        }

    float4v acc[4][2];
#pragma unroll
    for (int mt = 0; mt < 4; mt++)
#pragma unroll
        for (int nt = 0; nt < 2; nt++) acc[mt][nt] = (float4v)(0.f);
#pragma unroll
    for (int mt = 0; mt < 4; mt++)
#pragma unroll
        for (int kt = 0; kt < 3; kt++) {
            half8 af = *(const half8*)&w1s[(kt * 64 + mt * 16 + lcol) * WROW + q * 8];
#pragma unroll
            for (int nt = 0; nt < 2; nt++)
                acc[mt][nt] = __builtin_amdgcn_mfma_f32_16x16x32_f16(
                    af, bf[nt][kt], acc[mt][nt], 0, 0, 0);
        }

    __builtin_amdgcn_wave_barrier();
#pragma unroll
    for (int pp = 0; pp < 2; pp++)
#pragma unroll
        for (int nt = 0; nt < 2; nt++) {
            half4 gh;
#pragma unroll
            for (int r = 0; r < 4; r++)
                gh[r] = (_Float16)(fast_tanh(acc[pp][nt][r]) *
                                   fast_sigmoid(acc[pp + 2][nt][r]));
            *(half4*)&Gs[wv][nt * 16 + lcol][pp * 16 + q * 4] = gh;
        }
    __builtin_amdgcn_wave_barrier();

    const int tcol = t0 + n0;
    half4 skv[2][2];
    if (!FIRST) {
#pragma unroll
        for (int mt = 0; mt < 2; mt++)
#pragma unroll
            for (int nt = 0; nt < 2; nt++) {
                int t = tcol + nt * 16 + lcol;
                skv[mt][nt] = *(const half4*)(skip +
                    ((size_t)b * T + t) * SKIPC + mt * 16 + q * 4);
            }
    }

    float4v zacc[4][2];
#pragma unroll
    for (int mt = 0; mt < 4; mt++)
#pragma unroll
        for (int nt = 0; nt < 2; nt++) zacc[mt][nt] = (float4v)(0.f);
    half8 gb[2];
#pragma unroll
    for (int nt = 0; nt < 2; nt++)
        gb[nt] = *(const half8*)&Gs[wv][nt * 16 + lcol][q * 8];
#pragma unroll
    for (int mt = 0; mt < 4; mt++) {
        half8 af = *(const half8*)&w2s[(mt * 16 + lcol) * WROW + q * 8];
#pragma unroll
        for (int nt = 0; nt < 2; nt++)
            zacc[mt][nt] = __builtin_amdgcn_mfma_f32_16x16x32_f16(
                af, gb[nt], zacc[mt][nt], 0, 0, 0);
    }

#pragma unroll
    for (int mt = 0; mt < 2; mt++)
#pragma unroll
        for (int nt = 0; nt < 2; nt++) {
            int t = tcol + nt * 16 + lcol;
            size_t off = ((size_t)b * T + t) * RES + mt * 16 + q * 4;
            half4 hw;
#pragma unroll
            for (int r = 0; r < 4; r++)
                hw[r] = (_Float16)((float)hAcore[mt][nt][r] + zacc[mt][nt][r]);
            *(half4*)(h_out + off) = hw;
        }
#pragma unroll
    for (int mt = 0; mt < 2; mt++)
#pragma unroll
        for (int nt = 0; nt < 2; nt++) {
            int t = tcol + nt * 16 + lcol;
            size_t off = ((size_t)b * T + t) * SKIPC + mt * 16 + q * 4;
            half4 sw;
#pragma unroll
            for (int r = 0; r < 4; r++) {
                float z = zAs[mt][nt][r] + zacc[mt + 2][nt][r];
                sw[r] = (_Float16)(FIRST ? z : (float)skv[mt][nt][r] + z);
            }
            *(half4*)(skip + off) = sw;
        }
}

// ---------------- post2 ----------------
#define P2_TILE 256
__global__ __launch_bounds__(256) void post2_kernel(
        const _Float16* __restrict__ skip,
        const float* __restrict__ w,    // [16][32][3]
        float* __restrict__ out16) {
    __shared__ float st[(P2_TILE + 2) * 33];

    const int tid = threadIdx.x;
    int b, t0;
    decode_bt(blockIdx.x, P2_TILE, b, t0);

    const int total8 = ((P2_TILE + 2) * 32) / 8;
    for (int ci = tid; ci < total8; ci += 256) {
        int flat = ci * 8;
        int row = flat >> 5;
        int c = flat & 31;
        int ts = t0 - 2 + row;
        half8 v = (half8)(_Float16)0.f;
        if (ts >= 0)
            v = *(const half8*)(skip + ((size_t)b * T + ts) * SKIPC + c);
        float* dst = &st[row * 33 + c];
#pragma unroll
        for (int r = 0; r < 8; r++)
            dst[r] = fast_tanh((float)v[r]);
    }
    __syncthreads();

    const int t = t0 + tid;
    float acc[16];
#pragma unroll
    for (int o = 0; o < 16; o++) acc[o] = 0.f;
#pragma unroll 4
    for (int c = 0; c < 32; c++) {
        float s0 = st[(tid + 0) * 33 + c];
        float s1 = st[(tid + 1) * 33 + c];
        float s2 = st[(tid + 2) * 33 + c];
#pragma unroll
        for (int o = 0; o < 16; o++) {
            const float* wo = w + (o * 32 + c) * 3;
            acc[o] += wo[0] * s0 + wo[1] * s1 + wo[2] * s2;
        }
    }
#pragma unroll
    for (int o = 0; o < 16; o++)
        out16[((size_t)(b * 16 + o)) * T + t] = fast_tanh(acc[o]);
}

// ---------------- post3 ----------------
__global__ void post3_kernel(const float* __restrict__ in16,
                             const float* __restrict__ w,    // [8][16][3]
                             float* __restrict__ out8) {
    int b, t0;
    decode_bt(blockIdx.x, 256, b, t0);
    int t = t0 + threadIdx.x;
    float acc[8];
#pragma unroll
    for (int o = 0; o < 8; o++) acc[o] = 0.f;
    for (int c = 0; c < 16; c++) {
        const float* sc = in16 + ((size_t)(b * 16 + c)) * T;
        float v2 = sc[t];
        float v1 = (t >= 1) ? sc[t - 1] : 0.f;
        float v0 = (t >= 2) ? sc[t - 2] : 0.f;
#pragma unroll
        for (int o = 0; o < 8; o++) {
            const float* wo = w + (o * 16 + c) * 3;
            acc[o] += wo[0] * v0 + wo[1] * v1 + wo[2] * v2;
        }
    }
#pragma unroll
    for (int o = 0; o < 8; o++)
        out8[((size_t)(b * 8 + o)) * T + t] = fast_tanh(acc[o]);
}

// ---------------- post4 + vnn fused ----------------
__global__ __launch_bounds__(256) void post4_vnn_kernel(
        const float* __restrict__ in8,   // [B][8][T]
        const float* __restrict__ w4,    // [1][8][3]
        const float* __restrict__ w1,    // [1][1][16]
        const float* __restrict__ w2,    // [6][1][16]
        float* __restrict__ out) {       // [B][T]
    __shared__ float s1[272];

    const int tid = threadIdx.x;
    int b, t0;
    decode_bt(blockIdx.x, 256, b, t0);

    for (int i = tid; i < 271; i += 256) {
        int c = t0 - 15 + i;
        float o1 = 0.f;
        if (c >= 0) {
            float acc = 0.f;
#pragma unroll
            for (int ch = 0; ch < 8; ch++) {
                const float* sc = in8 + ((size_t)(b * 8 + ch)) * T;
                float v2 = sc[c];
                float v1 = (c >= 1) ? sc[c - 1] : 0.f;
                float v0 = (c >= 2) ? sc[c - 2] : 0.f;
                const float* wo = w4 + ch * 3;
                acc += wo[0] * v0 + wo[1] * v1 + wo[2] * v2;
            }
            o1 = fast_tanh(acc);
        }
        s1[i] = o1;
    }
    __syncthreads();

    const int t = t0 + tid;
    float lin = 0.f;
    float s[6];
#pragma unroll
    for (int qq = 0; qq < 6; qq++) s[qq] = 0.f;
#pragma unroll
    for (int k = 0; k < 16; k++) {
        float tap = s1[tid + k];
        lin += w1[k] * tap;
#pragma unroll
        for (int qq = 0; qq < 6; qq++) s[qq] += w2[qq * 16 + k] * tap;
    }
    float quad = s[0] * s[3] + s[1] * s[4] + s[2] * s[5];
    out[(size_t)b * T + t] = lin + quad;
}

extern "C" void kernel_launch(void* const* d_in, const int* in_sizes, int n_in,
                              void* d_out, int out_size, void* d_ws, size_t ws_size,
                              hipStream_t stream) {
    const float* x       = (const float*)d_in[0];
    const float* conv1_w = (const float*)d_in[1];
    const float* res_w1  = (const float*)d_in[2];
    const float* res_w2  = (const float*)d_in[3];
    const float* post2_w = (const float*)d_in[4];
    const float* post3_w = (const float*)d_in[5];
    const float* post4_w = (const float*)d_in[6];
    const float* vnn1_w  = (const float*)d_in[7];
    const float* vnn2_w  = (const float*)d_in[8];
    float* out = (float*)d_out;

    char* ws = (char*)d_ws;
    const size_t SZ_HF   = (size_t)B * RES * T * 2;
    const size_t SZ_SKIP = (size_t)B * SKIPC * T * 2;
    const size_t SZ_O16  = (size_t)B * 16 * T * 4;
    const size_t SZ_O8   = (size_t)B * 8 * T * 4;
    _Float16*  hA    = (_Float16*)(ws);
    _Float16*  hB    = (_Float16*)(ws + SZ_HF);
    _Float16*  skip  = (_Float16*)(ws + 2 * SZ_HF);
    float*     out16 = (float*)(ws + 2 * SZ_HF + SZ_SKIP);
    float*     out8  = (float*)(ws + 2 * SZ_HF + SZ_SKIP + SZ_O16);
    _Float16*  w1f   = (_Float16*)(ws + 2 * SZ_HF + SZ_SKIP + SZ_O16 + SZ_O8);
    _Float16*  w2f   = (_Float16*)(ws + 2 * SZ_HF + SZ_SKIP + SZ_O16 + SZ_O8
                                      + (size_t)NDIL * 3 * 64 * 32 * 2);

    dim3 blk(256);
    dim3 grd(125 * 8);     // tile 256
    dim3 grdR(250 * 8);    // tile 128

    repack_weights_f16<<<dim3((NDIL * 3 * 64 * 32 + 255) / 256), blk, 0, stream>>>(
        res_w1, res_w2, w1f, w2f);

    conv1_kernel<<<grd, blk, 0, stream>>>(x, conv1_w, hA);

    const int  plan_l[13] = {0, 2, 4, 6, 7, 8, 9, 11, 13, 15, 17, 18, 19};
    const bool plan_p[13] = {true, true, true, false, false, false, true,
                             true, true, true, false, false, false};

    const _Float16* cur = hA;
    _Float16* nxt = hB;
    for (int i = 0; i < 13; i++) {
        int l = plan_l[i];
        int ilA = l % NDIL;
        int d1 = 1 << ilA;
        const _Float16* w1Ap = w1f + (size_t)ilA * 3 * 64 * 32;
        const _Float16* w2Ap = w2f + (size_t)ilA * 64 * 32;
        if (plan_p[i]) {
            int ilB = (l + 1) % NDIL;
            int d2 = 1 << ilB;
            const _Float16* w1Bp = w1f + (size_t)ilB * 3 * 64 * 32;
            const _Float16* w2Bp = w2f + (size_t)ilB * 64 * 32;
            if (i == 0)
                res_pair_mfma<true><<<grdR, blk, 0, stream>>>(
                    cur, nxt, skip, w1Ap, w2Ap, w1Bp, w2Bp, d1, d2);
            else
                res_pair_mfma<false><<<grdR, blk, 0, stream>>>(
                    cur, nxt, skip, w1Ap, w2Ap, w1Bp, w2Bp, d1, d2);
        } else {
            res_layer_mfma<false><<<grdR, blk, 0, stream>>>(
                cur, nxt, skip, w1Ap, w2Ap, d1);
        }
        const _Float16* tmp = nxt;
        nxt = (_Float16*)cur;
        cur = tmp;
    }

    post2_kernel<<<grd, blk, 0, stream>>>(skip, post2_w, out16);
    post3_kernel<<<grd, blk, 0, stream>>>(out16, post3_w, out8);
    post4_vnn_kernel<<<grd, blk, 0, stream>>>(out8, post4_w, vnn1_w, vnn2_w, out);
}

// Round 21
// 443.737 us; speedup vs baseline: 1.2914x; 1.0337x over previous
//
#include <hip/hip_runtime.h>
#include <math.h>

#define T 32000
#define B 8
#define RES 32
#define SKIPC 32
#define NDIL 10
#define NLAYERS 20

typedef __attribute__((ext_vector_type(8))) _Float16 half8;
typedef __attribute__((ext_vector_type(4))) _Float16 half4;
typedef __attribute__((ext_vector_type(4))) float float4v;

// ---------------- fast transcendentals ----------------
__device__ __forceinline__ float fast_rcp(float x) { return __builtin_amdgcn_rcpf(x); }
__device__ __forceinline__ float fast_exp2(float x) { return __builtin_amdgcn_exp2f(x); }
__device__ __forceinline__ float fast_sigmoid(float x) {
    return fast_rcp(1.f + fast_exp2(-1.4426950408889634f * x));
}
__device__ __forceinline__ float fast_tanh(float x) {
    return 1.f - 2.f * fast_rcp(1.f + fast_exp2(2.8853900817779268f * x));
}

// XCD-affine decode (R18 win): b = g & 7 pins each batch to one XCD's L2.
__device__ __forceinline__ void decode_bt(int g, int tile, int& b, int& t0) {
    b = g & 7;
    t0 = (g >> 3) * tile;
}

// ---- weight staging into LDS, padded stride 40 halfs (80 B) ----
#define WROW 40
__device__ __forceinline__ void stage_w1(const _Float16* __restrict__ w1l,
                                         _Float16* w1s, int tid) {
    for (int i = tid; i < 192 * 4; i += 256) {
        int row = i >> 2, c = (i & 3) * 8;
        *(half8*)&w1s[row * WROW + c] = *(const half8*)(w1l + row * 32 + c);
    }
}
__device__ __forceinline__ void stage_w2(const _Float16* __restrict__ w2l,
                                         _Float16* w2s, int tid) {
    for (int i = tid; i < 64 * 4; i += 256) {
        int row = i >> 2, c = (i & 3) * 8;
        *(half8*)&w2s[row * WROW + c] = *(const half8*)(w2l + row * 32 + c);
    }
}

// ---------------- weight repack to fp16 ----------------
__global__ void repack_weights_f16(const float* __restrict__ w1,
                                   const float* __restrict__ w2,
                                   _Float16* __restrict__ w1f,
                                   _Float16* __restrict__ w2f) {
    int idx = blockIdx.x * blockDim.x + threadIdx.x;
    if (idx < NDIL * 3 * 64 * 32) {
        int i = idx;
        int c = i % 32; i /= 32;
        int o = i % 64; i /= 64;
        int kt = i % 3; i /= 3;
        int l = i;
        w1f[idx] = (_Float16)w1[((l * 64 + o) * 32 + c) * 3 + kt];
    }
    if (idx < NDIL * 64 * 32) {
        w2f[idx] = (_Float16)w2[idx];
    }
}

// ---------------- conv1: [B,1,T] -> h[B][T][RES] fp16 channel-contiguous ----
__global__ void conv1_kernel(const float* __restrict__ x,
                             const float* __restrict__ w,   // [32][1][3]
                             _Float16* __restrict__ h) {
    int b, t0;
    decode_bt(blockIdx.x, 256, b, t0);
    int t = t0 + threadIdx.x;
    const float* xb = x + (size_t)b * T;
    float x2 = xb[t];
    float x1 = (t >= 1) ? xb[t - 1] : 0.f;
    float x0 = (t >= 2) ? xb[t - 2] : 0.f;
    _Float16* hr = h + ((size_t)b * T + t) * RES;
#pragma unroll
    for (int o = 0; o < RES; o += 8) {
        half8 v;
#pragma unroll
        for (int r = 0; r < 8; r++)
            v[r] = (_Float16)(w[(o + r) * 3 + 0] * x0 + w[(o + r) * 3 + 1] * x1
                            + w[(o + r) * 3 + 2] * x2);
        *(half8*)(hr + o) = v;
    }
}

// ---------------- F5: layers with d=1,2,4,8,16 fused (halo sum 62 <= 64) ----
// buf[2][192][40]: cols [t0-64, t0+128) double-buffered in LDS; all 5 layers'
// intermediate h never touches HBM. 9 passes (2 each for l=0..3 — left-halo
// pass predicated on u >= 128-R_out — and 1 for l=4). Per-layer weights
// staged to LDS. Skip accumulated in fp32 registers -> ONE RMW for 5 layers.
// LDS 61440 B -> 2 blocks/CU.
template <bool FIRST>
__global__ __launch_bounds__(256) void res_f5(
        const _Float16* __restrict__ h_in, _Float16* __restrict__ h_out,
        _Float16* __restrict__ skip,
        const _Float16* __restrict__ w1f,   // layers 0..4 at l*3*64*32
        const _Float16* __restrict__ w2f) { // layers 0..4 at l*64*32
    __shared__ _Float16 buf[2][192][40];    // 30720 B
    __shared__ _Float16 Gs[4][32][40];      // 10240 B
    __shared__ _Float16 w1s[192 * WROW];    // 15360 B
    __shared__ _Float16 w2s[64 * WROW];     //  5120 B  => 61440

    const int tid = threadIdx.x;
    int b, t0;
    decode_bt(blockIdx.x, 128, b, t0);
    const int lane = tid & 63;
    const int wv = tid >> 6;
    const int n0 = wv * 32;
    const int lcol = lane & 15;
    const int q = lane >> 4;
    const half8 zero8 = (half8)(_Float16)0.f;

    // ---- stage input cols [t0-64, t0+128) into buf[0] (zero for col<0) ----
    if (tid < 192) {
        int col = t0 - 64 + tid;
        bool ok = col >= 0;
        const _Float16* src = h_in + ((size_t)b * T + (ok ? col : 0)) * RES;
#pragma unroll
        for (int c = 0; c < 4; c++) {
            half8 v = ok ? *(const half8*)(src + c * 8) : zero8;
            *(half8*)&buf[0][tid][c * 8] = v;
        }
    }

    float ska[2][2][4];
#pragma unroll
    for (int mt = 0; mt < 2; mt++)
#pragma unroll
        for (int nt = 0; nt < 2; nt++)
#pragma unroll
            for (int r = 0; r < 4; r++) ska[mt][nt][r] = 0.f;

    half4 hfin[2][2];

    const int DIL[5]  = {1, 2, 4, 8, 16};
    const int ROUT[5] = {60, 56, 48, 32, 0};   // halo still needed after layer l

    int cur = 0;
#pragma unroll
    for (int l = 0; l < 5; l++) {
        __syncthreads();   // buf writes visible; prior weight reads done
        stage_w1(w1f + (size_t)l * 3 * 64 * 32, w1s, tid);
        stage_w2(w2f + (size_t)l * 64 * 32, w2s, tid);
        __syncthreads();   // weights staged (covers buf[0] staging at l=0 too)

        const int d = DIL[l];
        const int ro = ROUT[l];

#pragma unroll
        for (int s = 0; s < 2; s++) {
            if (ro == 0 && s == 0) continue;   // last layer: core pass only

            // ---- taps from LDS: row = (s? u+64 : u-64), tap = row-(2-kt)*d ----
            half8 bf_[2][3];
#pragma unroll
            for (int nt = 0; nt < 2; nt++) {
                int u = n0 + nt * 16 + lcol;
                int row = s ? (u + 64) : (u - 64);
#pragma unroll
                for (int kt = 0; kt < 3; kt++) {
                    int tr = row - (2 - kt) * d;
                    tr = tr < 0 ? 0 : tr;      // dead lanes clamped; discarded
                    bf_[nt][kt] = *(const half8*)&buf[cur][tr][q * 8];
                }
            }

            // ---- conv GEMM ----
            float4v acc[4][2];
#pragma unroll
            for (int mt = 0; mt < 4; mt++)
#pragma unroll
                for (int nt = 0; nt < 2; nt++) acc[mt][nt] = (float4v)(0.f);
#pragma unroll
            for (int mt = 0; mt < 4; mt++)
#pragma unroll
                for (int kt = 0; kt < 3; kt++) {
                    half8 af = *(const half8*)&w1s[(kt * 64 + mt * 16 + lcol) * WROW + q * 8];
#pragma unroll
                    for (int nt = 0; nt < 2; nt++)
                        acc[mt][nt] = __builtin_amdgcn_mfma_f32_16x16x32_f16(
                            af, bf_[nt][kt], acc[mt][nt], 0, 0, 0);
                }

            // ---- gate -> wave-private Gs ----
            __builtin_amdgcn_wave_barrier();
#pragma unroll
            for (int pp = 0; pp < 2; pp++)
#pragma unroll
                for (int nt = 0; nt < 2; nt++) {
                    half4 gh;
#pragma unroll
                    for (int r = 0; r < 4; r++)
                        gh[r] = (_Float16)(fast_tanh(acc[pp][nt][r]) *
                                           fast_sigmoid(acc[pp + 2][nt][r]));
                    *(half4*)&Gs[wv][nt * 16 + lcol][pp * 16 + q * 4] = gh;
                }
            __builtin_amdgcn_wave_barrier();

            // ---- 1x1 GEMM ----
            float4v zacc[4][2];
#pragma unroll
            for (int mt = 0; mt < 4; mt++)
#pragma unroll
                for (int nt = 0; nt < 2; nt++) zacc[mt][nt] = (float4v)(0.f);
            half8 gb[2];
#pragma unroll
            for (int nt = 0; nt < 2; nt++)
                gb[nt] = *(const half8*)&Gs[wv][nt * 16 + lcol][q * 8];
#pragma unroll
            for (int mt = 0; mt < 4; mt++) {
                half8 af = *(const half8*)&w2s[(mt * 16 + lcol) * WROW + q * 8];
#pragma unroll
                for (int nt = 0; nt < 2; nt++)
                    zacc[mt][nt] = __builtin_amdgcn_mfma_f32_16x16x32_f16(
                        af, gb[nt], zacc[mt][nt], 0, 0, 0);
            }

            // ---- epilogue: residual from bufin, write bufout (live only) ----
#pragma unroll
            for (int mt = 0; mt < 2; mt++)
#pragma unroll
                for (int nt = 0; nt < 2; nt++) {
                    int u = n0 + nt * 16 + lcol;
                    int row = s ? (u + 64) : (u - 64);
                    bool live = s ? true : (u >= 128 - ro);
                    int col = t0 - 128 + s * 128 + u;
                    bool ok = col >= 0;
                    int rr = row < 0 ? 0 : row;
                    half4 hv = *(const half4*)&buf[cur][rr][mt * 16 + q * 4];
                    half4 hw;
#pragma unroll
                    for (int r = 0; r < 4; r++)
                        hw[r] = ok ? (_Float16)((float)hv[r] + zacc[mt][nt][r])
                                   : (_Float16)0.f;
                    if (l == 4) {
                        hfin[mt][nt] = hw;      // only s==1 for l=4
                    } else if (live) {
                        *(half4*)&buf[cur ^ 1][row][mt * 16 + q * 4] = hw;
                    }
                    if (s == 1) {
#pragma unroll
                        for (int r = 0; r < 4; r++)
                            ska[mt][nt][r] += zacc[mt + 2][nt][r];
                    }
                }
        }
        cur ^= 1;
    }

    // ---- final: h_out core + single skip RMW for all 5 layers ----
    const int tcol = t0 + n0;
    half4 skv[2][2];
    if (!FIRST) {
#pragma unroll
        for (int mt = 0; mt < 2; mt++)
#pragma unroll
            for (int nt = 0; nt < 2; nt++) {
                int t = tcol + nt * 16 + lcol;
                skv[mt][nt] = *(const half4*)(skip +
                    ((size_t)b * T + t) * SKIPC + mt * 16 + q * 4);
            }
    }
#pragma unroll
    for (int mt = 0; mt < 2; mt++)
#pragma unroll
        for (int nt = 0; nt < 2; nt++) {
            int t = tcol + nt * 16 + lcol;
            *(half4*)(h_out + ((size_t)b * T + t) * RES + mt * 16 + q * 4) =
                hfin[mt][nt];
            half4 sw;
#pragma unroll
            for (int r = 0; r < 4; r++) {
                float z = ska[mt][nt][r];
                sw[r] = (_Float16)(FIRST ? z : (float)skv[mt][nt][r] + z);
            }
            *(half4*)(skip + ((size_t)b * T + t) * SKIPC + mt * 16 + q * 4) = sw;
        }
}

// ---------------- single residual layer (weights in LDS, R19 proven) --------
template <bool FIRST>
__global__ __launch_bounds__(256) void res_layer_mfma(
        const _Float16* __restrict__ h_in, _Float16* __restrict__ h_out,
        _Float16* __restrict__ skip,
        const _Float16* __restrict__ w1l,   // [3][64][32]
        const _Float16* __restrict__ w2l,   // [64][32]
        int d) {
    __shared__ _Float16 Gs[4][32][40];
    __shared__ _Float16 w1s[192 * WROW];
    __shared__ _Float16 w2s[64 * WROW];

    const int tid = threadIdx.x;
    int b, t0;
    decode_bt(blockIdx.x, 128, b, t0);
    const int lane = tid & 63;
    const int wv = tid >> 6;
    const int n0 = wv * 32;
    const int lcol = lane & 15;
    const int q = lane >> 4;
    const _Float16* hb = h_in + (size_t)b * T * RES;

    stage_w1(w1l, w1s, tid);
    stage_w2(w2l, w2s, tid);

    half8 bf[2][3];
    const half8 zero8 = (half8)(_Float16)0.f;
    if (t0 >= 2 * d) {
#pragma unroll
        for (int nt = 0; nt < 2; nt++)
#pragma unroll
            for (int kt = 0; kt < 3; kt++) {
                int tb = t0 + n0 + nt * 16 + lcol - (2 - kt) * d;
                bf[nt][kt] = *(const half8*)(hb + (size_t)tb * RES + q * 8);
            }
    } else {
#pragma unroll
        for (int nt = 0; nt < 2; nt++)
#pragma unroll
            for (int kt = 0; kt < 3; kt++) {
                int tb = t0 + n0 + nt * 16 + lcol - (2 - kt) * d;
                bool ok = tb >= 0;
                half8 p = *(const half8*)(hb + (size_t)(ok ? tb : 0) * RES + q * 8);
                bf[nt][kt] = ok ? p : zero8;
            }
    }
    __syncthreads();

    float4v acc[4][2];
#pragma unroll
    for (int mt = 0; mt < 4; mt++)
#pragma unroll
        for (int nt = 0; nt < 2; nt++) acc[mt][nt] = (float4v)(0.f);
#pragma unroll
    for (int mt = 0; mt < 4; mt++)
#pragma unroll
        for (int kt = 0; kt < 3; kt++) {
            half8 af = *(const half8*)&w1s[(kt * 64 + mt * 16 + lcol) * WROW + q * 8];
#pragma unroll
            for (int nt = 0; nt < 2; nt++)
                acc[mt][nt] = __builtin_amdgcn_mfma_f32_16x16x32_f16(
                    af, bf[nt][kt], acc[mt][nt], 0, 0, 0);
        }

#pragma unroll
    for (int pp = 0; pp < 2; pp++)
#pragma unroll
        for (int nt = 0; nt < 2; nt++) {
            half4 gh;
#pragma unroll
            for (int r = 0; r < 4; r++)
                gh[r] = (_Float16)(fast_tanh(acc[pp][nt][r]) *
                                   fast_sigmoid(acc[pp + 2][nt][r]));
            *(half4*)&Gs[wv][nt * 16 + lcol][pp * 16 + q * 4] = gh;
        }
    __builtin_amdgcn_wave_barrier();

    const int tcol = t0 + n0;
    half4 skv[2][2];
    if (!FIRST) {
#pragma unroll
        for (int mt = 0; mt < 2; mt++)
#pragma unroll
            for (int nt = 0; nt < 2; nt++) {
                int t = tcol + nt * 16 + lcol;
                skv[mt][nt] = *(const half4*)(skip +
                    ((size_t)b * T + t) * SKIPC + mt * 16 + q * 4);
            }
    }

    float4v zacc[4][2];
#pragma unroll
    for (int mt = 0; mt < 4; mt++)
#pragma unroll
        for (int nt = 0; nt < 2; nt++) zacc[mt][nt] = (float4v)(0.f);
    half8 gb[2];
#pragma unroll
    for (int nt = 0; nt < 2; nt++)
        gb[nt] = *(const half8*)&Gs[wv][nt * 16 + lcol][q * 8];
#pragma unroll
    for (int mt = 0; mt < 4; mt++) {
        half8 af = *(const half8*)&w2s[(mt * 16 + lcol) * WROW + q * 8];
#pragma unroll
        for (int nt = 0; nt < 2; nt++)
            zacc[mt][nt] = __builtin_amdgcn_mfma_f32_16x16x32_f16(
                af, gb[nt], zacc[mt][nt], 0, 0, 0);
    }

#pragma unroll
    for (int mt = 0; mt < 2; mt++)
#pragma unroll
        for (int nt = 0; nt < 2; nt++) {
            int t = tcol + nt * 16 + lcol;
            size_t off = ((size_t)b * T + t) * RES + mt * 16 + q * 4;
            half4 hv = *(const half4*)(h_in + off);
            half4 hw;
#pragma unroll
            for (int r = 0; r < 4; r++)
                hw[r] = (_Float16)((float)hv[r] + zacc[mt][nt][r]);
            *(half4*)(h_out + off) = hw;
        }
#pragma unroll
    for (int mt = 0; mt < 2; mt++)
#pragma unroll
        for (int nt = 0; nt < 2; nt++) {
            int t = tcol + nt * 16 + lcol;
            size_t off = ((size_t)b * T + t) * SKIPC + mt * 16 + q * 4;
            half4 sw;
#pragma unroll
            for (int r = 0; r < 4; r++) {
                float z = zacc[mt + 2][nt][r];
                sw[r] = (_Float16)(FIRST ? z : (float)skv[mt][nt][r] + z);
            }
            *(half4*)(skip + off) = sw;
        }
}

// ---------------- fused layer PAIR (d2 <= 64), weights in LDS (R19) ---------
template <bool FIRST>
__global__ __launch_bounds__(256) void res_pair_mfma(
        const _Float16* __restrict__ h_in, _Float16* __restrict__ h_out,
        _Float16* __restrict__ skip,
        const _Float16* __restrict__ w1A, const _Float16* __restrict__ w2A,
        const _Float16* __restrict__ w1B, const _Float16* __restrict__ w2B,
        int d1, int d2) {
    __shared__ _Float16 hAa[256][40];
    __shared__ _Float16 Gs[4][32][40];
    __shared__ _Float16 w1s[192 * WROW];
    __shared__ _Float16 w2s[64 * WROW];

    const int tid = threadIdx.x;
    int b, t0;
    decode_bt(blockIdx.x, 128, b, t0);
    const int lane = tid & 63;
    const int wv = tid >> 6;
    const int n0 = wv * 32;
    const int lcol = lane & 15;
    const int q = lane >> 4;
    const _Float16* hb = h_in + (size_t)b * T * RES;
    const half8 zero8 = (half8)(_Float16)0.f;

    float zAs[2][2][4];
    half4 hAcore[2][2];

    stage_w1(w1A, w1s, tid);
    stage_w2(w2A, w2s, tid);
    __syncthreads();

    // ===== Phase A =====
#pragma unroll 1
    for (int s = 0; s < 2; s++) {
        const int base = t0 - 128 + s * 128;

        half8 bf[2][3];
        if (base >= 2 * d1) {
#pragma unroll
            for (int nt = 0; nt < 2; nt++)
#pragma unroll
                for (int kt = 0; kt < 3; kt++) {
                    int tb = base + n0 + nt * 16 + lcol - (2 - kt) * d1;
                    bf[nt][kt] = *(const half8*)(hb + (size_t)tb * RES + q * 8);
                }
        } else {
#pragma unroll
            for (int nt = 0; nt < 2; nt++)
#pragma unroll
                for (int kt = 0; kt < 3; kt++) {
                    int tb = base + n0 + nt * 16 + lcol - (2 - kt) * d1;
                    bool ok = tb >= 0;
                    half8 p = *(const half8*)(hb + (size_t)(ok ? tb : 0) * RES + q * 8);
                    bf[nt][kt] = ok ? p : zero8;
                }
        }

        float4v acc[4][2];
#pragma unroll
        for (int mt = 0; mt < 4; mt++)
#pragma unroll
            for (int nt = 0; nt < 2; nt++) acc[mt][nt] = (float4v)(0.f);
#pragma unroll
        for (int mt = 0; mt < 4; mt++)
#pragma unroll
            for (int kt = 0; kt < 3; kt++) {
                half8 af = *(const half8*)&w1s[(kt * 64 + mt * 16 + lcol) * WROW + q * 8];
#pragma unroll
                for (int nt = 0; nt < 2; nt++)
                    acc[mt][nt] = __builtin_amdgcn_mfma_f32_16x16x32_f16(
                        af, bf[nt][kt], acc[mt][nt], 0, 0, 0);
            }

        __builtin_amdgcn_wave_barrier();
#pragma unroll
        for (int pp = 0; pp < 2; pp++)
#pragma unroll
            for (int nt = 0; nt < 2; nt++) {
                half4 gh;
#pragma unroll
                for (int r = 0; r < 4; r++)
                    gh[r] = (_Float16)(fast_tanh(acc[pp][nt][r]) *
                                       fast_sigmoid(acc[pp + 2][nt][r]));
                *(half4*)&Gs[wv][nt * 16 + lcol][pp * 16 + q * 4] = gh;
            }
        __builtin_amdgcn_wave_barrier();

        float4v zacc[4][2];
#pragma unroll
        for (int mt = 0; mt < 4; mt++)
#pragma unroll
            for (int nt = 0; nt < 2; nt++) zacc[mt][nt] = (float4v)(0.f);
        half8 gb[2];
#pragma unroll
        for (int nt = 0; nt < 2; nt++)
            gb[nt] = *(const half8*)&Gs[wv][nt * 16 + lcol][q * 8];
#pragma unroll
        for (int mt = 0; mt < 4; mt++) {
            half8 af = *(const half8*)&w2s[(mt * 16 + lcol) * WROW + q * 8];
#pragma unroll
            for (int nt = 0; nt < 2; nt++)
                zacc[mt][nt] = __builtin_amdgcn_mfma_f32_16x16x32_f16(
                    af, gb[nt], zacc[mt][nt], 0, 0, 0);
        }

#pragma unroll
        for (int mt = 0; mt < 2; mt++)
#pragma unroll
            for (int nt = 0; nt < 2; nt++) {
                int t = base + n0 + nt * 16 + lcol;
                bool ok = t >= 0;
                size_t off = ((size_t)b * T + (ok ? t : 0)) * RES + mt * 16 + q * 4;
                half4 hv = *(const half4*)(h_in + off);
                half4 hw;
#pragma unroll
                for (int r = 0; r < 4; r++)
                    hw[r] = ok ? (_Float16)((float)hv[r] + zacc[mt][nt][r])
                               : (_Float16)0.f;
                *(half4*)&hAa[s * 128 + n0 + nt * 16 + lcol][mt * 16 + q * 4] = hw;
                if (s == 1) {
                    hAcore[mt][nt] = hw;
#pragma unroll
                    for (int r = 0; r < 4; r++)
                        zAs[mt][nt][r] = zacc[mt + 2][nt][r];
                }
            }
    }
    __syncthreads();

    stage_w1(w1B, w1s, tid);
    stage_w2(w2B, w2s, tid);
    __syncthreads();

    // ===== Phase B =====
    half8 bf[2][3];
#pragma unroll
    for (int nt = 0; nt < 2; nt++)
#pragma unroll
        for (int kt = 0; kt < 3; kt++) {
            int rel = 128 + n0 + nt * 16 + lcol - (2 - kt) * d2;
            bf[nt][kt] = *(const half8*)&hAa[rel][q * 8];
        }

    float4v acc[4][2];
#pragma unroll
    for (int mt = 0; mt < 4; mt++)
#pragma unroll
        for (int nt = 0; nt < 2; nt++) acc[mt][nt] = (float4v)(0.f);
#pragma unroll
    for (int mt = 0; mt < 4; mt++)
#pragma unroll
        for (int kt = 0; kt < 3; kt++) {
            half8 af = *(const half8*)&w1s[(kt * 64 + mt * 16 + lcol) * WROW + q * 8];
#pragma unroll
            for (int nt = 0; nt < 2; nt++)
                acc[mt][nt] = __builtin_amdgcn_mfma_f32_16x16x32_f16(
                    af, bf[nt][kt], acc[mt][nt], 0, 0, 0);
        }

    __builtin_amdgcn_wave_barrier();
#pragma unroll
    for (int pp = 0; pp < 2; pp++)
#pragma unroll
        for (int nt = 0; nt < 2; nt++) {
            half4 gh;
#pragma unroll
            for (int r = 0; r < 4; r++)
                gh[r] = (_Float16)(fast_tanh(acc[pp][nt][r]) *
                                   fast_sigmoid(acc[pp + 2][nt][r]));
            *(half4*)&Gs[wv][nt * 16 + lcol][pp * 16 + q * 4] = gh;
        }
    __builtin_amdgcn_wave_barrier();

    const int tcol = t0 + n0;
    half4 skv[2][2];
    if (!FIRST) {
#pragma unroll
        for (int mt = 0; mt < 2; mt++)
#pragma unroll
            for (int nt = 0; nt < 2; nt++) {
                int t = tcol + nt * 16 + lcol;
                skv[mt][nt] = *(const half4*)(skip +
                    ((size_t)b * T + t) * SKIPC + mt * 16 + q * 4);
            }
    }

    float4v zacc[4][2];
#pragma unroll
    for (int mt = 0; mt < 4; mt++)
#pragma unroll
        for (int nt = 0; nt < 2; nt++) zacc[mt][nt] = (float4v)(0.f);
    half8 gb[2];
#pragma unroll
    for (int nt = 0; nt < 2; nt++)
        gb[nt] = *(const half8*)&Gs[wv][nt * 16 + lcol][q * 8];
#pragma unroll
    for (int mt = 0; mt < 4; mt++) {
        half8 af = *(const half8*)&w2s[(mt * 16 + lcol) * WROW + q * 8];
#pragma unroll
        for (int nt = 0; nt < 2; nt++)
            zacc[mt][nt] = __builtin_amdgcn_mfma_f32_16x16x32_f16(
                af, gb[nt], zacc[mt][nt], 0, 0, 0);
    }

#pragma unroll
    for (int mt = 0; mt < 2; mt++)
#pragma unroll
        for (int nt = 0; nt < 2; nt++) {
            int t = tcol + nt * 16 + lcol;
            size_t off = ((size_t)b * T + t) * RES + mt * 16 + q * 4;
            half4 hw;
#pragma unroll
            for (int r = 0; r < 4; r++)
                hw[r] = (_Float16)((float)hAcore[mt][nt][r] + zacc[mt][nt][r]);
            *(half4*)(h_out + off) = hw;
        }
#pragma unroll
    for (int mt = 0; mt < 2; mt++)
#pragma unroll
        for (int nt = 0; nt < 2; nt++) {
            int t = tcol + nt * 16 + lcol;
            size_t off = ((size_t)b * T + t) * SKIPC + mt * 16 + q * 4;
            half4 sw;
#pragma unroll
            for (int r = 0; r < 4; r++) {
                float z = zAs[mt][nt][r] + zacc[mt + 2][nt][r];
                sw[r] = (_Float16)(FIRST ? z : (float)skv[mt][nt][r] + z);
            }
            *(half4*)(skip + off) = sw;
        }
}

// ---------------- post2 ----------------
#define P2_TILE 256
__global__ __launch_bounds__(256) void post2_kernel(
        const _Float16* __restrict__ skip,
        const float* __restrict__ w,    // [16][32][3]
        float* __restrict__ out16) {
    __shared__ float st[(P2_TILE + 2) * 33];

    const int tid = threadIdx.x;
    int b, t0;
    decode_bt(blockIdx.x, P2_TILE, b, t0);

    const int total8 = ((P2_TILE + 2) * 32) / 8;
    for (int ci = tid; ci < total8; ci += 256) {
        int flat = ci * 8;
        int row = flat >> 5;
        int c = flat & 31;
        int ts = t0 - 2 + row;
        half8 v = (half8)(_Float16)0.f;
        if (ts >= 0)
            v = *(const half8*)(skip + ((size_t)b * T + ts) * SKIPC + c);
        float* dst = &st[row * 33 + c];
#pragma unroll
        for (int r = 0; r < 8; r++)
            dst[r] = fast_tanh((float)v[r]);
    }
    __syncthreads();

    const int t = t0 + tid;
    float acc[16];
#pragma unroll
    for (int o = 0; o < 16; o++) acc[o] = 0.f;
#pragma unroll 4
    for (int c = 0; c < 32; c++) {
        float s0 = st[(tid + 0) * 33 + c];
        float s1 = st[(tid + 1) * 33 + c];
        float s2 = st[(tid + 2) * 33 + c];
#pragma unroll
        for (int o = 0; o < 16; o++) {
            const float* wo = w + (o * 32 + c) * 3;
            acc[o] += wo[0] * s0 + wo[1] * s1 + wo[2] * s2;
        }
    }
#pragma unroll
    for (int o = 0; o < 16; o++)
        out16[((size_t)(b * 16 + o)) * T + t] = fast_tanh(acc[o]);
}

// ---------------- post3 ----------------
__global__ void post3_kernel(const float* __restrict__ in16,
                             const float* __restrict__ w,    // [8][16][3]
                             float* __restrict__ out8) {
    int b, t0;
    decode_bt(blockIdx.x, 256, b, t0);
    int t = t0 + threadIdx.x;
    float acc[8];
#pragma unroll
    for (int o = 0; o < 8; o++) acc[o] = 0.f;
    for (int c = 0; c < 16; c++) {
        const float* sc = in16 + ((size_t)(b * 16 + c)) * T;
        float v2 = sc[t];
        float v1 = (t >= 1) ? sc[t - 1] : 0.f;
        float v0 = (t >= 2) ? sc[t - 2] : 0.f;
#pragma unroll
        for (int o = 0; o < 8; o++) {
            const float* wo = w + (o * 16 + c) * 3;
            acc[o] += wo[0] * v0 + wo[1] * v1 + wo[2] * v2;
        }
    }
#pragma unroll
    for (int o = 0; o < 8; o++)
        out8[((size_t)(b * 8 + o)) * T + t] = fast_tanh(acc[o]);
}

// ---------------- post4 + vnn fused ----------------
__global__ __launch_bounds__(256) void post4_vnn_kernel(
        const float* __restrict__ in8,   // [B][8][T]
        const float* __restrict__ w4,    // [1][8][3]
        const float* __restrict__ w1,    // [1][1][16]
        const float* __restrict__ w2,    // [6][1][16]
        float* __restrict__ out) {       // [B][T]
    __shared__ float s1[272];

    const int tid = threadIdx.x;
    int b, t0;
    decode_bt(blockIdx.x, 256, b, t0);

    for (int i = tid; i < 271; i += 256) {
        int c = t0 - 15 + i;
        float o1 = 0.f;
        if (c >= 0) {
            float acc = 0.f;
#pragma unroll
            for (int ch = 0; ch < 8; ch++) {
                const float* sc = in8 + ((size_t)(b * 8 + ch)) * T;
                float v2 = sc[c];
                float v1 = (c >= 1) ? sc[c - 1] : 0.f;
                float v0 = (c >= 2) ? sc[c - 2] : 0.f;
                const float* wo = w4 + ch * 3;
                acc += wo[0] * v0 + wo[1] * v1 + wo[2] * v2;
            }
            o1 = fast_tanh(acc);
        }
        s1[i] = o1;
    }
    __syncthreads();

    const int t = t0 + tid;
    float lin = 0.f;
    float s[6];
#pragma unroll
    for (int qq = 0; qq < 6; qq++) s[qq] = 0.f;
#pragma unroll
    for (int k = 0; k < 16; k++) {
        float tap = s1[tid + k];
        lin += w1[k] * tap;
#pragma unroll
        for (int qq = 0; qq < 6; qq++) s[qq] += w2[qq * 16 + k] * tap;
    }
    float quad = s[0] * s[3] + s[1] * s[4] + s[2] * s[5];
    out[(size_t)b * T + t] = lin + quad;
}

extern "C" void kernel_launch(void* const* d_in, const int* in_sizes, int n_in,
                              void* d_out, int out_size, void* d_ws, size_t ws_size,
                              hipStream_t stream) {
    const float* x       = (const float*)d_in[0];
    const float* conv1_w = (const float*)d_in[1];
    const float* res_w1  = (const float*)d_in[2];
    const float* res_w2  = (const float*)d_in[3];
    const float* post2_w = (const float*)d_in[4];
    const float* post3_w = (const float*)d_in[5];
    const float* post4_w = (const float*)d_in[6];
    const float* vnn1_w  = (const float*)d_in[7];
    const float* vnn2_w  = (const float*)d_in[8];
    float* out = (float*)d_out;

    char* ws = (char*)d_ws;
    const size_t SZ_HF   = (size_t)B * RES * T * 2;
    const size_t SZ_SKIP = (size_t)B * SKIPC * T * 2;
    const size_t SZ_O16  = (size_t)B * 16 * T * 4;
    const size_t SZ_O8   = (size_t)B * 8 * T * 4;
    _Float16*  hA    = (_Float16*)(ws);
    _Float16*  hB    = (_Float16*)(ws + SZ_HF);
    _Float16*  skip  = (_Float16*)(ws + 2 * SZ_HF);
    float*     out16 = (float*)(ws + 2 * SZ_HF + SZ_SKIP);
    float*     out8  = (float*)(ws + 2 * SZ_HF + SZ_SKIP + SZ_O16);
    _Float16*  w1f   = (_Float16*)(ws + 2 * SZ_HF + SZ_SKIP + SZ_O16 + SZ_O8);
    _Float16*  w2f   = (_Float16*)(ws + 2 * SZ_HF + SZ_SKIP + SZ_O16 + SZ_O8
                                      + (size_t)NDIL * 3 * 64 * 32 * 2);

    dim3 blk(256);
    dim3 grd(125 * 8);     // tile 256
    dim3 grdR(250 * 8);    // tile 128

    repack_weights_f16<<<dim3((NDIL * 3 * 64 * 32 + 255) / 256), blk, 0, stream>>>(
        res_w1, res_w2, w1f, w2f);

    conv1_kernel<<<grd, blk, 0, stream>>>(x, conv1_w, hA);

    const size_t W1L = (size_t)3 * 64 * 32;   // 6144
    const size_t W2L = (size_t)64 * 32;       // 2048

    const _Float16* cur = hA;
    _Float16* nxt = hB;

    // layers 0-4 fused (d = 1,2,4,8,16)
    res_f5<true><<<grdR, blk, 0, stream>>>(cur, nxt, skip, w1f, w2f);
    { const _Float16* tmp = nxt; nxt = (_Float16*)cur; cur = tmp; }

    // pair (5,6): d1=32, d2=64
    res_pair_mfma<false><<<grdR, blk, 0, stream>>>(
        cur, nxt, skip, w1f + 5 * W1L, w2f + 5 * W2L,
        w1f + 6 * W1L, w2f + 6 * W2L, 32, 64);
    { const _Float16* tmp = nxt; nxt = (_Float16*)cur; cur = tmp; }

    // singles 7,8,9 (d = 128,256,512)
    for (int il = 7; il <= 9; il++) {
        res_layer_mfma<false><<<grdR, blk, 0, stream>>>(
            cur, nxt, skip, w1f + (size_t)il * W1L, w2f + (size_t)il * W2L, 1 << il);
        const _Float16* tmp = nxt; nxt = (_Float16*)cur; cur = tmp;
    }

    // layers 10-14 fused (same weight layers 0-4)
    res_f5<false><<<grdR, blk, 0, stream>>>(cur, nxt, skip, w1f, w2f);
    { const _Float16* tmp = nxt; nxt = (_Float16*)cur; cur = tmp; }

    // pair (15,16)
    res_pair_mfma<false><<<grdR, blk, 0, stream>>>(
        cur, nxt, skip, w1f + 5 * W1L, w2f + 5 * W2L,
        w1f + 6 * W1L, w2f + 6 * W2L, 32, 64);
    { const _Float16* tmp = nxt; nxt = (_Float16*)cur; cur = tmp; }

    // singles 17,18,19
    for (int il = 7; il <= 9; il++) {
        res_layer_mfma<false><<<grdR, blk, 0, stream>>>(
            cur, nxt, skip, w1f + (size_t)il * W1L, w2f + (size_t)il * W2L, 1 << il);
        const _Float16* tmp = nxt; nxt = (_Float16*)cur; cur = tmp;
    }

    post2_kernel<<<grd, blk, 0, stream>>>(skip, post2_w, out16);
    post3_kernel<<<grd, blk, 0, stream>>>(out16, post3_w, out8);
    post4_vnn_kernel<<<grd, blk, 0, stream>>>(out8, post4_w, vnn1_w, vnn2_w, out);
}